// Round 8
// baseline (1580.688 us; speedup 1.0000x reference)
//
#include <hip/hip_runtime.h>
#include <cstddef>

// ---------------- problem dims ----------------
constexpr int BB   = 4;
constexpr int LX   = 126975;
constexpr int H0   = 4096, W0 = 61;          // c_in spatial
constexpr int C1   = 128, H1 = 1025, W1 = 16;
constexpr int C2   = 256, H2 = 513,  W2 = 8;
constexpr int C3   = 128;
constexpr int NN   = H2 * W2;                // 4104
constexpr int NSPLIT = 15;                   // attention j-splits
constexpr int JSPAN  = 288;                  // 32-aligned; 15*288 >= 4104
constexpr int NPAD   = 4104;                 // partial-row stride (16B-aligned)

// ---------------- workspace layout (float offsets), lifetime-overlapped ----
constexpr size_t SZ_H1    = (size_t)BB * C1 * H1 * W1;        // 8,396,800
constexpr size_t SZ_P2    = (size_t)BB * C2 * NN;             // 4,202,496
constexpr size_t SZ_P3    = (size_t)BB * C3 * NN;             // 2,101,248
constexpr size_t SZ_F     = (size_t)BB * 32 * NN;             //   525,312
constexpr size_t SZ_QK    = (size_t)BB * 4 * NN;              //    65,664
constexpr size_t SZ_ACCP  = (size_t)NSPLIT * BB * 32 * NPAD;  // 7,879,680
constexpr size_t SZ_ML    = (size_t)NSPLIT * BB * 2 * NPAD;   //   492,480

// Region A [0, 8,396,800): h1 (conv1->conv2); p3a/p3b (conv3->c5);
//   then accp/ml (flash->combine).
constexpr size_t OFF_H1   = 0;
constexpr size_t OFF_P3A  = 0;
constexpr size_t OFF_P3B  = SZ_P3;              // ends 4,202,496 < 8,396,800
constexpr size_t OFF_ACCP = 0;                  // after c5 (p3a/b dead)
constexpr size_t OFF_ML   = OFF_ACCP + SZ_ACCP; // ends 8,372,160 < 8,396,800
constexpr size_t RB       = SZ_H1;              // 8,396,800
constexpr size_t OFF_P2   = RB;
constexpr size_t OFF_F1   = RB;                 // reuses p2 (dead after conv3)
constexpr size_t OFF_F2   = OFF_F1 + SZ_F;
constexpr size_t OFF_Q    = OFF_F2 + SZ_F;
constexpr size_t OFF_K    = OFF_Q  + SZ_QK;
constexpr size_t OFF_V    = OFF_K  + SZ_QK;
constexpr size_t OFF_SA   = OFF_V  + SZ_F;
constexpr size_t OFF_SC   = OFF_SA + SZ_F;
constexpr size_t OFF_EN   = RB + SZ_P2;         // 4096 floats
constexpr size_t OFF_W2T  = OFF_EN + 4096;      // 3200*256 = 819,200
constexpr size_t OFF_W3T  = OFF_W2T + 819200;   // 2304*128 = 294,912
// total = 13,717,504 floats = 54.9 MB

__device__ __forceinline__ float frelu(float x) { return x > 0.f ? x : 0.f; }

// ========= weight transpose: w2T[k][256], w3T[k][128] (oc-minor) =========
// grid (3200), block 256.
__global__ __launch_bounds__(256) void k_wtrans(const float* __restrict__ w2,
                                                const float* __restrict__ w3,
                                                float* __restrict__ w2T,
                                                float* __restrict__ w3T) {
  const int k = blockIdx.x, oc = threadIdx.x;
  w2T[(size_t)k * 256 + oc] = w2[(size_t)oc * 3200 + k];
  if (k < 2304 && oc < 128) w3T[(size_t)k * 128 + oc] = w3[(size_t)oc * 2304 + k];
}

// ================= conv1: 8x8 s4 p4, cin=1, 128 oc, +bias+relu ================
// grid (65, 16, 4), block 256.
__global__ __launch_bounds__(256) void k_conv1(const float* __restrict__ x,
                                               const float* __restrict__ w1,
                                               const float* __restrict__ b1,
                                               float* __restrict__ h1) {
  __shared__ __align__(16) float tile[68 * 68];
  const int oh0 = blockIdx.x * 16;
  const int oc0 = blockIdx.y * 8;
  const int b   = blockIdx.z;
  const int tid = threadIdx.x;
  const int ih0 = oh0 * 4 - 4;
  for (int e = tid; e < 68 * 68; e += 256) {
    int row = e / 68, col = e - row * 68;
    int ih = ih0 + row, iw = col - 4;
    float v = 0.f;
    if (ih >= 0 && ih < H0 && iw >= 0 && iw < W0) {
      int l   = ih * W0 + iw;
      int pos = (l >> 12) * 2048 + (l & 4095);
      if (pos < LX) v = x[(size_t)b * LX + pos];
    }
    tile[e] = v;
  }
  __syncthreads();
  const int oh_l = tid >> 4, ow = tid & 15;
  float acc[8];
#pragma unroll
  for (int o = 0; o < 8; ++o) acc[o] = 0.f;
#pragma unroll
  for (int kh = 0; kh < 8; ++kh) {
    const float* rp = &tile[(4 * oh_l + kh) * 68 + 4 * ow];
    float4 a0 = *(const float4*)rp;
    float4 a1 = *(const float4*)(rp + 4);
    float r[8] = {a0.x, a0.y, a0.z, a0.w, a1.x, a1.y, a1.z, a1.w};
#pragma unroll
    for (int kw = 0; kw < 8; ++kw) {
#pragma unroll
      for (int o = 0; o < 8; ++o)
        acc[o] = fmaf(r[kw], w1[(oc0 + o) * 64 + kh * 8 + kw], acc[o]);
    }
  }
  const int oh = oh0 + oh_l;
  if (oh < H1) {
#pragma unroll
    for (int o = 0; o < 8; ++o) {
      float v = frelu(acc[o] + b1[oc0 + o]);
      h1[(((size_t)b * C1 + oc0 + o) * H1 + oh) * W1 + ow] = v;
    }
  }
}

// ================= conv2: 5x5 s2 p2, full cin 128, +bias+relu ================
// grid (65, 4, 4), block 128 (2 waves): ocg = tid>>3 (16 grp x 4 oc = 64 oc),
// oh_l = tid&7 (oh tile 8).  Input tile in LDS; weights read directly from
// global w2T (oc-minor, coalesced float4, L1/L2-resident) -> LDS holds one
// operand only => FMA-bound (LDS ~960cyc vs FMA 1600cyc per wave per cc).
__global__ __launch_bounds__(128) void k_conv2(const float* __restrict__ h1,
                                               const float* __restrict__ w2T,
                                               const float* __restrict__ b2,
                                               float* __restrict__ p2) {
  __shared__ __align__(16) float tin[4 * 19 * 20];   // 1520 floats
  const int oh0 = blockIdx.x * 8;
  const int oc0 = blockIdx.y * 64;
  const int b   = blockIdx.z;
  const int tid = threadIdx.x;
  const int oh_l = tid & 7, ocg = tid >> 3;
  const int ih0 = oh0 * 2 - 2;
  float acc[4][8] = {};
  for (int cc = 0; cc < 32; ++cc) {
    __syncthreads();
    for (int e = tid; e < 4 * 19 * 16; e += 128) {
      int ci = e / 304, r = e - ci * 304;
      int tr = r >> 4, c = r & 15;
      int ih = ih0 + tr;
      int cin = cc * 4 + ci;
      float v = 0.f;
      if (ih >= 0 && ih < H1) v = h1[(((size_t)b * C1 + cin) * H1 + ih) * W1 + c];
      tin[(ci * 19 + tr) * 20 + c] = v;
    }
    __syncthreads();
#pragma unroll 1
    for (int ci = 0; ci < 4; ++ci) {
      const float* wbase = &w2T[(size_t)((cc * 4 + ci) * 25) * 256 + oc0 + ocg * 4];
#pragma unroll
      for (int kh = 0; kh < 5; ++kh) {
        const float* rp = &tin[(ci * 19 + 2 * oh_l + kh) * 20];
        float4 a0 = *(const float4*)rp;
        float4 a1 = *(const float4*)(rp + 4);
        float4 a2 = *(const float4*)(rp + 8);
        float4 a3 = *(const float4*)(rp + 12);
        float rr[19];
        rr[0] = 0.f; rr[1] = 0.f; rr[18] = 0.f;
        rr[2] = a0.x; rr[3] = a0.y; rr[4] = a0.z; rr[5] = a0.w;
        rr[6] = a1.x; rr[7] = a1.y; rr[8] = a1.z; rr[9] = a1.w;
        rr[10] = a2.x; rr[11] = a2.y; rr[12] = a2.z; rr[13] = a2.w;
        rr[14] = a3.x; rr[15] = a3.y; rr[16] = a3.z; rr[17] = a3.w;
#pragma unroll
        for (int kw = 0; kw < 5; ++kw) {
          float4 wv = *(const float4*)&wbase[(kh * 5 + kw) * 256];
#pragma unroll
          for (int ow = 0; ow < 8; ++ow) {
            float r = rr[2 * ow + kw];
            acc[0][ow] = fmaf(r, wv.x, acc[0][ow]);
            acc[1][ow] = fmaf(r, wv.y, acc[1][ow]);
            acc[2][ow] = fmaf(r, wv.z, acc[2][ow]);
            acc[3][ow] = fmaf(r, wv.w, acc[3][ow]);
          }
        }
      }
    }
  }
  const int oh = oh0 + oh_l;
  if (oh < H2) {
#pragma unroll
    for (int o = 0; o < 4; ++o) {
      int oc = oc0 + ocg * 4 + o;
      float bo = b2[oc];
      float* dst = &p2[((size_t)b * C2 + oc) * NN + oh * 8];
      *(float4*)dst       = make_float4(frelu(acc[o][0] + bo), frelu(acc[o][1] + bo),
                                        frelu(acc[o][2] + bo), frelu(acc[o][3] + bo));
      *(float4*)(dst + 4) = make_float4(frelu(acc[o][4] + bo), frelu(acc[o][5] + bo),
                                        frelu(acc[o][6] + bo), frelu(acc[o][7] + bo));
    }
  }
}

// ================= conv3: 3x3 s1 p1, cin-split 2x128, raw partials ============
// grid (65, 4, 4): by = oc_chunk(2) | half<<1.  block 128: 16ocg(4oc) x 8oh.
// Weights from global w3T; bias+relu deferred to k_c5 staging.
__global__ __launch_bounds__(128) void k_conv3(const float* __restrict__ p2,
                                               const float* __restrict__ w3T,
                                               float* __restrict__ p3a,
                                               float* __restrict__ p3b) {
  __shared__ __align__(16) float tin[8 * 10 * 12];   // 960
  const int oh0  = blockIdx.x * 8;
  const int oc0  = (blockIdx.y & 1) * 64;
  const int half = blockIdx.y >> 1;
  const int b    = blockIdx.z;
  const int tid  = threadIdx.x;
  const int oh_l = tid & 7, ocg = tid >> 3;
  float acc[4][8] = {};
  float* outp = half ? p3b : p3a;
  for (int cc = 0; cc < 16; ++cc) {
    __syncthreads();
    for (int e = tid; e < 640; e += 128) {
      int ci = e / 80, r = e - ci * 80;
      int tr = r >> 3, c = r & 7;
      int ih = oh0 - 1 + tr;
      int cin = half * 128 + cc * 8 + ci;
      float v = 0.f;
      if (ih >= 0 && ih < H2) v = p2[((size_t)b * C2 + cin) * NN + ih * 8 + c];
      tin[(ci * 10 + tr) * 12 + c] = v;
    }
    __syncthreads();
#pragma unroll 1
    for (int ci = 0; ci < 8; ++ci) {
      const float* wbase = &w3T[(size_t)((half * 128 + cc * 8 + ci) * 9) * 128 + oc0 + ocg * 4];
#pragma unroll
      for (int kh = 0; kh < 3; ++kh) {
        const float* rp = &tin[(ci * 10 + oh_l + kh) * 12];
        float4 a0 = *(const float4*)rp;
        float4 a1 = *(const float4*)(rp + 4);
        float rr[10];
        rr[0] = 0.f; rr[9] = 0.f;
        rr[1] = a0.x; rr[2] = a0.y; rr[3] = a0.z; rr[4] = a0.w;
        rr[5] = a1.x; rr[6] = a1.y; rr[7] = a1.z; rr[8] = a1.w;
#pragma unroll
        for (int kw = 0; kw < 3; ++kw) {
          float4 wv = *(const float4*)&wbase[(kh * 3 + kw) * 128];
#pragma unroll
          for (int ow = 0; ow < 8; ++ow) {
            float r = rr[ow + kw];
            acc[0][ow] = fmaf(r, wv.x, acc[0][ow]);
            acc[1][ow] = fmaf(r, wv.y, acc[1][ow]);
            acc[2][ow] = fmaf(r, wv.z, acc[2][ow]);
            acc[3][ow] = fmaf(r, wv.w, acc[3][ow]);
          }
        }
      }
    }
  }
  const int oh = oh0 + oh_l;
  if (oh < H2) {
#pragma unroll
    for (int o = 0; o < 4; ++o) {
      int oc = oc0 + ocg * 4 + o;
      float* dst = &outp[((size_t)b * C3 + oc) * NN + oh * 8];
      *(float4*)dst       = make_float4(acc[o][0], acc[o][1], acc[o][2], acc[o][3]);
      *(float4*)(dst + 4) = make_float4(acc[o][4], acc[o][5], acc[o][6], acc[o][7]);
    }
  }
}

// ========== fused conv5a + conv5c (3x3, cin128 -> 32+32) + BN + ReLU ==========
// grid (65, 4), block 128. Input = relu(p3a + p3b + b3) in staging.
__global__ __launch_bounds__(128) void k_c5(const float* __restrict__ p3a,
                                            const float* __restrict__ p3b,
                                            const float* __restrict__ b3,
                                            const float* __restrict__ wa,
                                            const float* __restrict__ sa5, const float* __restrict__ ba5,
                                            const float* __restrict__ ma5, const float* __restrict__ va5,
                                            const float* __restrict__ wc,
                                            const float* __restrict__ sc5, const float* __restrict__ bc5,
                                            const float* __restrict__ mc5, const float* __restrict__ vc5,
                                            float* __restrict__ f1, float* __restrict__ f2) {
  __shared__ __align__(16) float tin[8 * 10 * 12];  // 960
  __shared__ __align__(16) float twt[72 * 64];
  const int oh0 = blockIdx.x * 8;
  const int b   = blockIdx.y;
  const int tid = threadIdx.x;
  const int vocg = tid >> 3, oh_l = tid & 7;
  float acc[4][8] = {};
  for (int cc = 0; cc < 16; ++cc) {
    __syncthreads();
    for (int e = tid; e < 640; e += 128) {
      int ci = e / 80, r = e - ci * 80;
      int tr = r >> 3, c = r & 7;
      int ih = oh0 - 1 + tr;
      int cin = cc * 8 + ci;
      float v = 0.f;
      if (ih >= 0 && ih < H2) {
        size_t idx = ((size_t)b * C3 + cin) * NN + ih * 8 + c;
        v = frelu(p3a[idx] + p3b[idx] + b3[cin]);
      }
      tin[(ci * 10 + tr) * 12 + c] = v;
    }
    for (int e = tid; e < 4608; e += 128) {
      int voc_l = e & 63, t = e >> 6;
      const float* base = (voc_l < 32) ? (wa + (size_t)voc_l * 1152) : (wc + (size_t)(voc_l - 32) * 1152);
      twt[t * 64 + voc_l] = base[cc * 8 * 9 + t];
    }
    __syncthreads();
#pragma unroll 1
    for (int ci = 0; ci < 8; ++ci) {
#pragma unroll
      for (int kh = 0; kh < 3; ++kh) {
        const float* rp = &tin[(ci * 10 + oh_l + kh) * 12];
        float4 a0 = *(const float4*)rp;
        float4 a1 = *(const float4*)(rp + 4);
        float rr[10];
        rr[0] = 0.f; rr[9] = 0.f;
        rr[1] = a0.x; rr[2] = a0.y; rr[3] = a0.z; rr[4] = a0.w;
        rr[5] = a1.x; rr[6] = a1.y; rr[7] = a1.z; rr[8] = a1.w;
#pragma unroll
        for (int kw = 0; kw < 3; ++kw) {
          float4 wv = *(const float4*)&twt[(ci * 9 + kh * 3 + kw) * 64 + vocg * 4];
#pragma unroll
          for (int ow = 0; ow < 8; ++ow) {
            float r = rr[ow + kw];
            acc[0][ow] = fmaf(r, wv.x, acc[0][ow]);
            acc[1][ow] = fmaf(r, wv.y, acc[1][ow]);
            acc[2][ow] = fmaf(r, wv.z, acc[2][ow]);
            acc[3][ow] = fmaf(r, wv.w, acc[3][ow]);
          }
        }
      }
    }
  }
  const int oh = oh0 + oh_l;
  if (oh < H2) {
#pragma unroll
    for (int vv = 0; vv < 4; ++vv) {
      int voc = vocg * 4 + vv;
      bool A = voc < 32;
      int ci = voc & 31;
      float sN = A ? sa5[ci] : sc5[ci];
      float bN = A ? ba5[ci] : bc5[ci];
      float mN = A ? ma5[ci] : mc5[ci];
      float vN = A ? va5[ci] : vc5[ci];
      float inv = sN * rsqrtf(vN + 1e-5f);
      float sh  = bN - mN * inv;
      float* dst = (A ? f1 : f2) + ((size_t)b * 32 + ci) * NN + oh * 8;
      float y[8];
#pragma unroll
      for (int ow = 0; ow < 8; ++ow) y[ow] = frelu(acc[vv][ow] * inv + sh);
      *(float4*)dst       = make_float4(y[0], y[1], y[2], y[3]);
      *(float4*)(dst + 4) = make_float4(y[4], y[5], y[6], y[7]);
    }
  }
}

// ================= 1x1 convs for q, k, v =================
// grid (17, 40, 4), block 256.
__global__ __launch_bounds__(256) void k_qkv(const float* __restrict__ f1,
                                             const float* __restrict__ qw, const float* __restrict__ qbv,
                                             const float* __restrict__ kwp, const float* __restrict__ kbv,
                                             const float* __restrict__ vwp, const float* __restrict__ vbv,
                                             float* __restrict__ qo, float* __restrict__ ko,
                                             float* __restrict__ vo) {
  const int n = blockIdx.x * 256 + threadIdx.x;
  if (n >= NN) return;
  const int ocv = blockIdx.y, b = blockIdx.z;
  const float* w;
  float bias;
  float* dst;
  if (ocv < 4)      { w = qw + ocv * 32;        bias = qbv[ocv];     dst = qo + ((size_t)b * 4 + ocv) * NN; }
  else if (ocv < 8) { int o = ocv - 4; w = kwp + o * 32; bias = kbv[o]; dst = ko + ((size_t)b * 4 + o) * NN; }
  else              { int o = ocv - 8; w = vwp + o * 32; bias = vbv[o]; dst = vo + ((size_t)b * 32 + o) * NN; }
  float a = bias;
#pragma unroll
  for (int c = 0; c < 32; ++c) a = fmaf(f1[((size_t)b * 32 + c) * NN + n], w[c], a);
  dst[n] = a;
}

// ================= flash PAM attention, partial (j-split x15) =================
__device__ __forceinline__ float rmax32(const float (&p)[32]) {
  float x0 = p[0], x1 = p[1], x2 = p[2], x3 = p[3];
#pragma unroll
  for (int j = 4; j < 32; j += 4) {
    x0 = fmaxf(x0, p[j]); x1 = fmaxf(x1, p[j + 1]);
    x2 = fmaxf(x2, p[j + 2]); x3 = fmaxf(x3, p[j + 3]);
  }
  return fmaxf(fmaxf(x0, x1), fmaxf(x2, x3));
}
__device__ __forceinline__ float rsum32(const float (&p)[32]) {
  float x0 = p[0], x1 = p[1], x2 = p[2], x3 = p[3];
#pragma unroll
  for (int j = 4; j < 32; j += 4) { x0 += p[j]; x1 += p[j + 1]; x2 += p[j + 2]; x3 += p[j + 3]; }
  return (x0 + x1) + (x2 + x3);
}

// grid (17, 15, 4), block 256 (4 waves).
__global__ __launch_bounds__(256) void k_flash(const float* __restrict__ qb,
                                               const float* __restrict__ kb,
                                               const float* __restrict__ vb,
                                               float* __restrict__ accp,
                                               float* __restrict__ mlb) {
  __shared__ __align__(16) float ks[4 * 32];
  __shared__ __align__(16) float vs[32 * 32];
  const int tid = threadIdx.x;
  const int ia  = blockIdx.x * 256 + tid;
  const int sp  = blockIdx.y;
  const int b   = blockIdx.z;
  float q[4];
#pragma unroll
  for (int d = 0; d < 4; ++d)
    q[d] = (ia < NN) ? qb[((size_t)b * 4 + d) * NN + ia] : 0.f;
  float m = -1e30f, l = 0.f;
  float acc[32];
#pragma unroll
  for (int c = 0; c < 32; ++c) acc[c] = 0.f;
  const int jbeg = sp * JSPAN;
  const int jend = (jbeg + JSPAN < NN) ? jbeg + JSPAN : NN;
  const int cs = tid >> 3, j4 = (tid & 7) * 4;   // staging coords
  for (int j0 = jbeg; j0 < jend; j0 += 32) {
    const int nv = (jend - j0 < 32) ? jend - j0 : 32;
    __syncthreads();
    {
      const float* vsrc = &vb[((size_t)b * 32 + cs) * NN + j0 + j4];
      float4 v4;
      if (j4 + 4 <= nv) {
        v4 = *(const float4*)vsrc;
      } else {
        v4.x = (j4 + 0 < nv) ? vsrc[0] : 0.f;
        v4.y = (j4 + 1 < nv) ? vsrc[1] : 0.f;
        v4.z = (j4 + 2 < nv) ? vsrc[2] : 0.f;
        v4.w = (j4 + 3 < nv) ? vsrc[3] : 0.f;
      }
      *(float4*)&vs[cs * 32 + j4] = v4;
      if (tid < 32) {
        const int d = tid >> 3;
        const float* ksrc = &kb[((size_t)b * 4 + d) * NN + j0 + j4];
        float4 k4;
        if (j4 + 4 <= nv) {
          k4 = *(const float4*)ksrc;
        } else {
          k4.x = (j4 + 0 < nv) ? ksrc[0] : 0.f;
          k4.y = (j4 + 1 < nv) ? ksrc[1] : 0.f;
          k4.z = (j4 + 2 < nv) ? ksrc[2] : 0.f;
          k4.w = (j4 + 3 < nv) ? ksrc[3] : 0.f;
        }
        *(float4*)&ks[d * 32 + j4] = k4;
      }
    }
    __syncthreads();
    float p[32];
#pragma unroll
    for (int jj = 0; jj < 8; ++jj) {
      float4 k0 = *(const float4*)&ks[0 * 32 + 4 * jj];
      float4 k1 = *(const float4*)&ks[1 * 32 + 4 * jj];
      float4 k2 = *(const float4*)&ks[2 * 32 + 4 * jj];
      float4 k3 = *(const float4*)&ks[3 * 32 + 4 * jj];
      p[4 * jj + 0] = fmaf(q[0], k0.x, fmaf(q[1], k1.x, fmaf(q[2], k2.x, q[3] * k3.x)));
      p[4 * jj + 1] = fmaf(q[0], k0.y, fmaf(q[1], k1.y, fmaf(q[2], k2.y, q[3] * k3.y)));
      p[4 * jj + 2] = fmaf(q[0], k0.z, fmaf(q[1], k1.z, fmaf(q[2], k2.z, q[3] * k3.z)));
      p[4 * jj + 3] = fmaf(q[0], k0.w, fmaf(q[1], k1.w, fmaf(q[2], k2.w, q[3] * k3.w)));
    }
    if (nv < 32) {
#pragma unroll
      for (int j = 0; j < 32; ++j)
        if (j >= nv) p[j] = -1e30f;
    }
    float mn = fmaxf(m, rmax32(p));
    float f = __expf(m - mn);
    m = mn;
#pragma unroll
    for (int j = 0; j < 32; ++j) p[j] = __expf(p[j] - mn);
    l = fmaf(l, f, rsum32(p));
#pragma unroll
    for (int c = 0; c < 32; ++c) acc[c] *= f;
#pragma unroll
    for (int jj = 0; jj < 8; ++jj) {
      float4 p4 = make_float4(p[4 * jj], p[4 * jj + 1], p[4 * jj + 2], p[4 * jj + 3]);
#pragma unroll
      for (int c = 0; c < 32; ++c) {
        float4 vv = *(const float4*)&vs[c * 32 + 4 * jj];
        acc[c] = fmaf(p4.x, vv.x, fmaf(p4.y, vv.y, fmaf(p4.z, vv.z, fmaf(p4.w, vv.w, acc[c]))));
      }
    }
  }
  if (ia < NN) {
    const size_t sb4 = (size_t)(sp * 4 + b);
#pragma unroll
    for (int c = 0; c < 32; ++c)
      accp[(sb4 * 32 + c) * NPAD + ia] = acc[c];
    mlb[(sb4 * 2 + 0) * NPAD + ia] = m;
    mlb[(sb4 * 2 + 1) * NPAD + ia] = l;
  }
}

// ================= combine flash partials -> sa = gamma*attn@v + feat1 ============
// grid (17, 32, 4), block 256.
__global__ __launch_bounds__(256) void k_combine(const float* __restrict__ accp,
                                                 const float* __restrict__ mlb,
                                                 const float* __restrict__ f1,
                                                 const float* __restrict__ gamma,
                                                 float* __restrict__ sa) {
  const int n = blockIdx.x * 256 + threadIdx.x;
  if (n >= NN) return;
  const int c = blockIdx.y, b = blockIdx.z;
  float m[NSPLIT], l[NSPLIT];
#pragma unroll
  for (int s = 0; s < NSPLIT; ++s) {
    m[s] = mlb[((size_t)(s * 4 + b) * 2 + 0) * NPAD + n];
    l[s] = mlb[((size_t)(s * 4 + b) * 2 + 1) * NPAD + n];
  }
  float ms = m[0];
#pragma unroll
  for (int s = 1; s < NSPLIT; ++s) ms = fmaxf(ms, m[s]);
  float den = 0.f, num = 0.f;
#pragma unroll
  for (int s = 0; s < NSPLIT; ++s) {
    float w = __expf(m[s] - ms);
    den = fmaf(l[s], w, den);
    num = fmaf(w, accp[((size_t)(s * 4 + b) * 32 + c) * NPAD + n], num);
  }
  size_t o = ((size_t)b * 32 + c) * NN + n;
  sa[o] = gamma[0] * num / den + f1[o];
}

// ================= CAM: energy (atomic partials) ==============================
__global__ __launch_bounds__(256) void k_zero(float* __restrict__ p) {
  int i = blockIdx.x * 256 + threadIdx.x;
  if (i < 4096) p[i] = 0.f;
}

// grid (17, 4), block 256.
__global__ __launch_bounds__(256) void k_energy(const float* __restrict__ f2,
                                                float* __restrict__ energy) {
  __shared__ float fs[32 * 257];
  const int n0 = blockIdx.x * 256, b = blockIdx.y, tid = threadIdx.x;
  for (int e = tid; e < 32 * 256; e += 256) {
    int c = e >> 8, nl = e & 255;
    int n = n0 + nl;
    fs[c * 257 + nl] = (n < NN) ? f2[((size_t)b * 32 + c) * NN + n] : 0.f;
  }
  __syncthreads();
  const int cg = tid >> 4, dg = tid & 15;
  const int c0 = cg * 2, d0 = dg * 2;
  float e00 = 0.f, e01 = 0.f, e10 = 0.f, e11 = 0.f;
  for (int t = 0; t < 256; ++t) {
    float a0 = fs[c0 * 257 + t], a1 = fs[(c0 + 1) * 257 + t];
    float b0 = fs[d0 * 257 + t], b1 = fs[(d0 + 1) * 257 + t];
    e00 = fmaf(a0, b0, e00); e01 = fmaf(a0, b1, e01);
    e10 = fmaf(a1, b0, e10); e11 = fmaf(a1, b1, e11);
  }
  float* eb = energy + b * 1024;
  atomicAdd(&eb[c0 * 32 + d0], e00);
  atomicAdd(&eb[c0 * 32 + d0 + 1], e01);
  atomicAdd(&eb[(c0 + 1) * 32 + d0], e10);
  atomicAdd(&eb[(c0 + 1) * 32 + d0 + 1], e11);
}

// ======== CAM apply: cattn = softmax(maxE - E) rows; sc = g*cattn@f2 + f2 ========
// grid (65, 4), block 64.
__global__ __launch_bounds__(64) void k_cam(const float* __restrict__ f2,
                                            const float* __restrict__ energy,
                                            const float* __restrict__ gamma,
                                            float* __restrict__ sc) {
  __shared__ __align__(16) float cat[32 * 32];
  const int lane = threadIdx.x, b = blockIdx.y;
  const int n = blockIdx.x * 64 + lane;
  if (lane < 32) {
    const float* eb = energy + b * 1024 + lane * 32;
    float e[32];
#pragma unroll
    for (int d = 0; d < 32; ++d) e[d] = eb[d];
    float mn = e[0];
#pragma unroll
    for (int d = 1; d < 32; ++d) mn = fminf(mn, e[d]);
    float w[32];
    float sum = 0.f;
#pragma unroll
    for (int d = 0; d < 32; ++d) { w[d] = __expf(mn - e[d]); sum += w[d]; }
    float inv = 1.f / sum;
#pragma unroll
    for (int d = 0; d < 32; ++d) cat[lane * 32 + d] = w[d] * inv;
  }
  __syncthreads();
  const bool ok = n < NN;
  float f[32];
#pragma unroll
  for (int c = 0; c < 32; ++c) f[c] = ok ? f2[((size_t)b * 32 + c) * NN + n] : 0.f;
  const float g = gamma[0];
#pragma unroll
  for (int c = 0; c < 32; ++c) {
    float a = 0.f;
#pragma unroll
    for (int k4 = 0; k4 < 8; ++k4) {
      float4 cw = *(const float4*)&cat[c * 32 + 4 * k4];
      a = fmaf(cw.x, f[4 * k4], fmaf(cw.y, f[4 * k4 + 1], fmaf(cw.z, f[4 * k4 + 2], fmaf(cw.w, f[4 * k4 + 3], a))));
    }
    if (ok) sc[((size_t)b * 32 + c) * NN + n] = g * a + f[c];
  }
}

// ======== fused c51(sa)+BN+ReLU, c52(sc)+BN+ReLU, sum, conv8 1x1 -> out ========
// grid (65, 4), block 128.
__global__ __launch_bounds__(128) void k_final(const float* __restrict__ sa,
                                               const float* __restrict__ sc,
                                               const float* __restrict__ w51,
                                               const float* __restrict__ s51, const float* __restrict__ b51,
                                               const float* __restrict__ m51, const float* __restrict__ v51,
                                               const float* __restrict__ w52,
                                               const float* __restrict__ s52, const float* __restrict__ b52,
                                               const float* __restrict__ m52, const float* __restrict__ v52,
                                               const float* __restrict__ w8, const float* __restrict__ b8,
                                               float* __restrict__ out) {
  __shared__ __align__(16) float tin[2 * 8 * 10 * 12];  // 1920
  __shared__ __align__(16) float twt[72 * 64];          // 4608
  __shared__ float tmid[64 * 65];
  const int oh0 = blockIdx.x * 8;
  const int b   = blockIdx.y;
  const int tid = threadIdx.x;
  const int vocg = tid >> 3, oh_l = tid & 7;
  float acc[4][8] = {};
  for (int cc = 0; cc < 4; ++cc) {
    __syncthreads();
    for (int e = tid; e < 1280; e += 128) {
      int which = (e >= 640) ? 1 : 0;
      int r1 = e - which * 640;
      int ci = r1 / 80, r2 = r1 - ci * 80;
      int tr = r2 >> 3, c = r2 & 7;
      int ih = oh0 - 1 + tr;
      int cin = cc * 8 + ci;
      const float* src = which ? sc : sa;
      float v = 0.f;
      if (ih >= 0 && ih < H2) v = src[((size_t)b * 32 + cin) * NN + ih * 8 + c];
      tin[which * 960 + (ci * 10 + tr) * 12 + c] = v;
    }
    for (int e = tid; e < 4608; e += 128) {
      int voc_l = e & 63, t = e >> 6;
      const float* base = (voc_l < 32) ? (w51 + voc_l * 288) : (w52 + (voc_l - 32) * 288);
      twt[t * 64 + voc_l] = base[cc * 8 * 9 + t];
    }
    __syncthreads();
    const float* tbase = tin + (vocg < 8 ? 0 : 960);
#pragma unroll 1
    for (int ci = 0; ci < 8; ++ci) {
#pragma unroll
      for (int kh = 0; kh < 3; ++kh) {
        const float* rp = tbase + (ci * 10 + oh_l + kh) * 12;
        float4 a0 = *(const float4*)rp;
        float4 a1 = *(const float4*)(rp + 4);
        float rr[10];
        rr[0] = 0.f; rr[9] = 0.f;
        rr[1] = a0.x; rr[2] = a0.y; rr[3] = a0.z; rr[4] = a0.w;
        rr[5] = a1.x; rr[6] = a1.y; rr[7] = a1.z; rr[8] = a1.w;
#pragma unroll
        for (int kw = 0; kw < 3; ++kw) {
          float4 wv = *(const float4*)&twt[(ci * 9 + kh * 3 + kw) * 64 + vocg * 4];
#pragma unroll
          for (int ow = 0; ow < 8; ++ow) {
            float r = rr[ow + kw];
            acc[0][ow] = fmaf(r, wv.x, acc[0][ow]);
            acc[1][ow] = fmaf(r, wv.y, acc[1][ow]);
            acc[2][ow] = fmaf(r, wv.z, acc[2][ow]);
            acc[3][ow] = fmaf(r, wv.w, acc[3][ow]);
          }
        }
      }
    }
  }
  {
    float inv[4], sh[4];
#pragma unroll
    for (int vv = 0; vv < 4; ++vv) {
      int voc = vocg * 4 + vv;
      bool A = voc < 32;
      int ci = voc & 31;
      float sN = A ? s51[ci] : s52[ci];
      float bN = A ? b51[ci] : b52[ci];
      float mN = A ? m51[ci] : m52[ci];
      float vN = A ? v51[ci] : v52[ci];
      inv[vv] = sN * rsqrtf(vN + 1e-5f);
      sh[vv] = bN - mN * inv[vv];
    }
#pragma unroll
    for (int ow = 0; ow < 8; ++ow) {
      int pos = oh_l * 8 + ow;
#pragma unroll
      for (int vv = 0; vv < 4; ++vv) {
        float y = acc[vv][ow] * inv[vv] + sh[vv];
        tmid[pos * 65 + vocg * 4 + vv] = frelu(y);
      }
    }
  }
  __syncthreads();
  {
    const int o = tid >> 6, pos = tid & 63;
    const int oh = oh0 + (pos >> 3), ow = pos & 7;
    float a = b8[o];
    const float* wrow = w8 + o * 32;
#pragma unroll
    for (int c = 0; c < 32; ++c)
      a = fmaf(tmid[pos * 65 + c] + tmid[pos * 65 + 32 + c], wrow[c], a);
    if (oh < H2) out[((size_t)b * 2 + o) * NN + oh * 8 + ow] = a;
  }
}

// =========================== launcher ===========================
extern "C" void kernel_launch(void* const* d_in, const int* in_sizes, int n_in,
                              void* d_out, int out_size, void* d_ws, size_t ws_size,
                              hipStream_t stream) {
  (void)in_sizes; (void)n_in; (void)out_size; (void)ws_size;
  const float* x      = (const float*)d_in[0];
  const float* w1     = (const float*)d_in[1];
  const float* b1     = (const float*)d_in[2];
  const float* w2     = (const float*)d_in[3];
  const float* b2     = (const float*)d_in[4];
  const float* w3     = (const float*)d_in[5];
  const float* b3     = (const float*)d_in[6];
  const float* c5a_w  = (const float*)d_in[7];
  const float* bn5a_s = (const float*)d_in[8];
  const float* bn5a_b = (const float*)d_in[9];
  const float* bn5a_m = (const float*)d_in[10];
  const float* bn5a_v = (const float*)d_in[11];
  const float* c5c_w  = (const float*)d_in[12];
  const float* bn5c_s = (const float*)d_in[13];
  const float* bn5c_b = (const float*)d_in[14];
  const float* bn5c_m = (const float*)d_in[15];
  const float* bn5c_v = (const float*)d_in[16];
  const float* c51_w  = (const float*)d_in[17];
  const float* bn51_s = (const float*)d_in[18];
  const float* bn51_b = (const float*)d_in[19];
  const float* bn51_m = (const float*)d_in[20];
  const float* bn51_v = (const float*)d_in[21];
  const float* c52_w  = (const float*)d_in[22];
  const float* bn52_s = (const float*)d_in[23];
  const float* bn52_b = (const float*)d_in[24];
  const float* bn52_m = (const float*)d_in[25];
  const float* bn52_v = (const float*)d_in[26];
  const float* pam_qw = (const float*)d_in[27];
  const float* pam_qb = (const float*)d_in[28];
  const float* pam_kw = (const float*)d_in[29];
  const float* pam_kb = (const float*)d_in[30];
  const float* pam_vw = (const float*)d_in[31];
  const float* pam_vb = (const float*)d_in[32];
  const float* pgamma = (const float*)d_in[33];
  const float* cgamma = (const float*)d_in[34];
  const float* c8_w   = (const float*)d_in[35];
  const float* c8_b   = (const float*)d_in[36];

  float* W    = (float*)d_ws;
  float* h1   = W + OFF_H1;
  float* p2   = W + OFF_P2;
  float* p3a  = W + OFF_P3A;
  float* p3b  = W + OFF_P3B;
  float* f1   = W + OFF_F1;
  float* f2   = W + OFF_F2;
  float* qbuf = W + OFF_Q;
  float* kbuf = W + OFF_K;
  float* vbuf = W + OFF_V;
  float* sab  = W + OFF_SA;
  float* scb  = W + OFF_SC;
  float* accp = W + OFF_ACCP;
  float* mlb  = W + OFF_ML;
  float* enb  = W + OFF_EN;
  float* w2T  = W + OFF_W2T;
  float* w3T  = W + OFF_W3T;
  float* outp = (float*)d_out;

  k_wtrans<<<dim3(3200), 256, 0, stream>>>(w2, w3, w2T, w3T);
  k_conv1<<<dim3(65, 16, 4), 256, 0, stream>>>(x, w1, b1, h1);
  k_conv2<<<dim3(65, 4, 4), 128, 0, stream>>>(h1, w2T, b2, p2);
  k_conv3<<<dim3(65, 4, 4), 128, 0, stream>>>(p2, w3T, p3a, p3b);
  k_c5<<<dim3(65, 4), 128, 0, stream>>>(p3a, p3b, b3,
                                        c5a_w, bn5a_s, bn5a_b, bn5a_m, bn5a_v,
                                        c5c_w, bn5c_s, bn5c_b, bn5c_m, bn5c_v,
                                        f1, f2);
  k_qkv<<<dim3(17, 40, 4), 256, 0, stream>>>(f1, pam_qw, pam_qb, pam_kw, pam_kb,
                                             pam_vw, pam_vb, qbuf, kbuf, vbuf);
  k_zero<<<dim3(16), 256, 0, stream>>>(enb);
  k_flash<<<dim3(17, NSPLIT, 4), 256, 0, stream>>>(qbuf, kbuf, vbuf, accp, mlb);
  k_energy<<<dim3(17, 4), 256, 0, stream>>>(f2, enb);
  k_combine<<<dim3(17, 32, 4), 256, 0, stream>>>(accp, mlb, f1, pgamma, sab);
  k_cam<<<dim3(65, 4), 64, 0, stream>>>(f2, enb, cgamma, scb);
  k_final<<<dim3(65, 4), 128, 0, stream>>>(sab, scb,
                                           c51_w, bn51_s, bn51_b, bn51_m, bn51_v,
                                           c52_w, bn52_s, bn52_b, bn52_m, bn52_v,
                                           c8_w, c8_b, outp);
}

// Round 9
// 1563.333 us; speedup vs baseline: 1.0111x; 1.0111x over previous
//
#include <hip/hip_runtime.h>
#include <cstddef>

// ---------------- problem dims ----------------
constexpr int BB   = 4;
constexpr int LX   = 126975;
constexpr int H0   = 4096, W0 = 61;          // c_in spatial
constexpr int C1   = 128, H1 = 1025, W1 = 16;
constexpr int C2   = 256, H2 = 513,  W2 = 8;
constexpr int C3   = 128;
constexpr int NN   = H2 * W2;                // 4104
constexpr int NSPLIT = 15;                   // attention j-splits
constexpr int JSPAN  = 288;                  // 32-aligned; 15*288 >= 4104
constexpr int NPAD   = 4104;                 // partial-row stride (16B-aligned)

// ---------------- workspace layout (float offsets), lifetime-overlapped ----
constexpr size_t SZ_H1    = (size_t)BB * C1 * H1 * W1;        // 8,396,800
constexpr size_t SZ_P2    = (size_t)BB * C2 * NN;             // 4,202,496
constexpr size_t SZ_P3    = (size_t)BB * C3 * NN;             // 2,101,248
constexpr size_t SZ_F     = (size_t)BB * 32 * NN;             //   525,312
constexpr size_t SZ_QK    = (size_t)BB * 4 * NN;              //    65,664
constexpr size_t SZ_ACCP  = (size_t)NSPLIT * BB * 32 * NPAD;  // 7,879,680
constexpr size_t SZ_ML    = (size_t)NSPLIT * BB * 2 * NPAD;   //   492,480

// Region A [0, 8,396,800): h1 (conv1->conv2); p3a/p3b (conv3->c5);
//   then accp/ml (flash->combine).
constexpr size_t OFF_H1   = 0;
constexpr size_t OFF_P3A  = 0;
constexpr size_t OFF_P3B  = SZ_P3;              // ends 4,202,496 < 8,396,800
constexpr size_t OFF_ACCP = 0;                  // after c5 (p3a/b dead)
constexpr size_t OFF_ML   = OFF_ACCP + SZ_ACCP; // ends 8,372,160 < 8,396,800
constexpr size_t RB       = SZ_H1;              // 8,396,800
constexpr size_t OFF_P2   = RB;
constexpr size_t OFF_F1   = RB;                 // reuses p2 (dead after conv3)
constexpr size_t OFF_F2   = OFF_F1 + SZ_F;
constexpr size_t OFF_Q    = OFF_F2 + SZ_F;
constexpr size_t OFF_K    = OFF_Q  + SZ_QK;
constexpr size_t OFF_V    = OFF_K  + SZ_QK;
constexpr size_t OFF_SA   = OFF_V  + SZ_F;
constexpr size_t OFF_SC   = OFF_SA + SZ_F;
constexpr size_t OFF_EN   = RB + SZ_P2;         // 4096 floats
constexpr size_t OFF_W2T  = OFF_EN + 4096;      // 3200*256 = 819,200
constexpr size_t OFF_W3T  = OFF_W2T + 819200;   // 2304*128 = 294,912
// total = 13,717,504 floats = 54.9 MB

__device__ __forceinline__ float frelu(float x) { return x > 0.f ? x : 0.f; }

// ========= weight transpose: w2T[k][256], w3T[k][128] (oc-minor) =========
// grid (3200), block 256.
__global__ __launch_bounds__(256) void k_wtrans(const float* __restrict__ w2,
                                                const float* __restrict__ w3,
                                                float* __restrict__ w2T,
                                                float* __restrict__ w3T) {
  const int k = blockIdx.x, oc = threadIdx.x;
  w2T[(size_t)k * 256 + oc] = w2[(size_t)oc * 3200 + k];
  if (k < 2304 && oc < 128) w3T[(size_t)k * 128 + oc] = w3[(size_t)oc * 2304 + k];
}

// ================= conv1: 8x8 s4 p4, cin=1, 128 oc, +bias+relu ================
// grid (65, 16, 4), block 256.
__global__ __launch_bounds__(256) void k_conv1(const float* __restrict__ x,
                                               const float* __restrict__ w1,
                                               const float* __restrict__ b1,
                                               float* __restrict__ h1) {
  __shared__ __align__(16) float tile[68 * 68];
  const int oh0 = blockIdx.x * 16;
  const int oc0 = blockIdx.y * 8;
  const int b   = blockIdx.z;
  const int tid = threadIdx.x;
  const int ih0 = oh0 * 4 - 4;
  for (int e = tid; e < 68 * 68; e += 256) {
    int row = e / 68, col = e - row * 68;
    int ih = ih0 + row, iw = col - 4;
    float v = 0.f;
    if (ih >= 0 && ih < H0 && iw >= 0 && iw < W0) {
      int l   = ih * W0 + iw;
      int pos = (l >> 12) * 2048 + (l & 4095);
      if (pos < LX) v = x[(size_t)b * LX + pos];
    }
    tile[e] = v;
  }
  __syncthreads();
  const int oh_l = tid >> 4, ow = tid & 15;
  float acc[8];
#pragma unroll
  for (int o = 0; o < 8; ++o) acc[o] = 0.f;
#pragma unroll
  for (int kh = 0; kh < 8; ++kh) {
    const float* rp = &tile[(4 * oh_l + kh) * 68 + 4 * ow];
    float4 a0 = *(const float4*)rp;
    float4 a1 = *(const float4*)(rp + 4);
    float r[8] = {a0.x, a0.y, a0.z, a0.w, a1.x, a1.y, a1.z, a1.w};
#pragma unroll
    for (int kw = 0; kw < 8; ++kw) {
#pragma unroll
      for (int o = 0; o < 8; ++o)
        acc[o] = fmaf(r[kw], w1[(oc0 + o) * 64 + kh * 8 + kw], acc[o]);
    }
  }
  const int oh = oh0 + oh_l;
  if (oh < H1) {
#pragma unroll
    for (int o = 0; o < 8; ++o) {
      float v = frelu(acc[o] + b1[oc0 + o]);
      h1[(((size_t)b * C1 + oc0 + o) * H1 + oh) * W1 + ow] = v;
    }
  }
}

// ================= conv2: 5x5 s2 p2, full cin 128, +bias+relu ================
// grid (65, 8, 4), block 128 (2 waves): tile oh8 x oc32; thread = 2oc x 8ow.
// 2080 blocks x 2 waves = 4160 waves = 4 waves/SIMD (50% ceiling) -- restores
// the occupancy lost in round 8 while keeping weights-from-global (w2T
// oc-minor, float2/thread, 64B/wave coalesced, L1-resident 12.8KB/cc slice).
__global__ __launch_bounds__(128) void k_conv2(const float* __restrict__ h1,
                                               const float* __restrict__ w2T,
                                               const float* __restrict__ b2,
                                               float* __restrict__ p2) {
  __shared__ __align__(16) float tin[4 * 19 * 20];   // 1520 floats
  const int oh0 = blockIdx.x * 8;
  const int oc0 = blockIdx.y * 32;
  const int b   = blockIdx.z;
  const int tid = threadIdx.x;
  const int oh_l = tid & 7, ocg = tid >> 3;          // ocg 0..15 -> 2 oc
  const int ih0 = oh0 * 2 - 2;
  float acc[2][8] = {};
  for (int cc = 0; cc < 32; ++cc) {
    __syncthreads();
    for (int e = tid; e < 4 * 19 * 16; e += 128) {
      int ci = e / 304, r = e - ci * 304;
      int tr = r >> 4, c = r & 15;
      int ih = ih0 + tr;
      int cin = cc * 4 + ci;
      float v = 0.f;
      if (ih >= 0 && ih < H1) v = h1[(((size_t)b * C1 + cin) * H1 + ih) * W1 + c];
      tin[(ci * 19 + tr) * 20 + c] = v;
    }
    __syncthreads();
#pragma unroll 1
    for (int ci = 0; ci < 4; ++ci) {
      const float* wbase = &w2T[(size_t)((cc * 4 + ci) * 25) * 256 + oc0 + ocg * 2];
#pragma unroll
      for (int kh = 0; kh < 5; ++kh) {
        const float* rp = &tin[(ci * 19 + 2 * oh_l + kh) * 20];
        float4 a0 = *(const float4*)rp;
        float4 a1 = *(const float4*)(rp + 4);
        float4 a2 = *(const float4*)(rp + 8);
        float4 a3 = *(const float4*)(rp + 12);
        float rr[19];
        rr[0] = 0.f; rr[1] = 0.f; rr[18] = 0.f;
        rr[2] = a0.x; rr[3] = a0.y; rr[4] = a0.z; rr[5] = a0.w;
        rr[6] = a1.x; rr[7] = a1.y; rr[8] = a1.z; rr[9] = a1.w;
        rr[10] = a2.x; rr[11] = a2.y; rr[12] = a2.z; rr[13] = a2.w;
        rr[14] = a3.x; rr[15] = a3.y; rr[16] = a3.z; rr[17] = a3.w;
#pragma unroll
        for (int kw = 0; kw < 5; ++kw) {
          float2 wv = *(const float2*)&wbase[(kh * 5 + kw) * 256];
#pragma unroll
          for (int ow = 0; ow < 8; ++ow) {
            float r = rr[2 * ow + kw];
            acc[0][ow] = fmaf(r, wv.x, acc[0][ow]);
            acc[1][ow] = fmaf(r, wv.y, acc[1][ow]);
          }
        }
      }
    }
  }
  const int oh = oh0 + oh_l;
  if (oh < H2) {
#pragma unroll
    for (int o = 0; o < 2; ++o) {
      int oc = oc0 + ocg * 2 + o;
      float bo = b2[oc];
      float* dst = &p2[((size_t)b * C2 + oc) * NN + oh * 8];
      *(float4*)dst       = make_float4(frelu(acc[o][0] + bo), frelu(acc[o][1] + bo),
                                        frelu(acc[o][2] + bo), frelu(acc[o][3] + bo));
      *(float4*)(dst + 4) = make_float4(frelu(acc[o][4] + bo), frelu(acc[o][5] + bo),
                                        frelu(acc[o][6] + bo), frelu(acc[o][7] + bo));
    }
  }
}

// ================= conv3: 3x3 s1 p1, cin-split 2x128, raw partials ============
// grid (65, 8, 4): by = oc_chunk(4: 32 oc) | half<<2.  block 128: 2oc x 8ow.
// 2080 blocks x 2 waves = 4 waves/SIMD.  Weights from global w3T; bias+relu
// deferred to k_c5 staging.
__global__ __launch_bounds__(128) void k_conv3(const float* __restrict__ p2,
                                               const float* __restrict__ w3T,
                                               float* __restrict__ p3a,
                                               float* __restrict__ p3b) {
  __shared__ __align__(16) float tin[8 * 10 * 12];   // 960
  const int oh0  = blockIdx.x * 8;
  const int oc0  = (blockIdx.y & 3) * 32;
  const int half = blockIdx.y >> 2;
  const int b    = blockIdx.z;
  const int tid  = threadIdx.x;
  const int oh_l = tid & 7, ocg = tid >> 3;
  float acc[2][8] = {};
  float* outp = half ? p3b : p3a;
  for (int cc = 0; cc < 16; ++cc) {
    __syncthreads();
    for (int e = tid; e < 640; e += 128) {
      int ci = e / 80, r = e - ci * 80;
      int tr = r >> 3, c = r & 7;
      int ih = oh0 - 1 + tr;
      int cin = half * 128 + cc * 8 + ci;
      float v = 0.f;
      if (ih >= 0 && ih < H2) v = p2[((size_t)b * C2 + cin) * NN + ih * 8 + c];
      tin[(ci * 10 + tr) * 12 + c] = v;
    }
    __syncthreads();
#pragma unroll 1
    for (int ci = 0; ci < 8; ++ci) {
      const float* wbase = &w3T[(size_t)((half * 128 + cc * 8 + ci) * 9) * 128 + oc0 + ocg * 2];
#pragma unroll
      for (int kh = 0; kh < 3; ++kh) {
        const float* rp = &tin[(ci * 10 + oh_l + kh) * 12];
        float4 a0 = *(const float4*)rp;
        float4 a1 = *(const float4*)(rp + 4);
        float rr[10];
        rr[0] = 0.f; rr[9] = 0.f;
        rr[1] = a0.x; rr[2] = a0.y; rr[3] = a0.z; rr[4] = a0.w;
        rr[5] = a1.x; rr[6] = a1.y; rr[7] = a1.z; rr[8] = a1.w;
#pragma unroll
        for (int kw = 0; kw < 3; ++kw) {
          float2 wv = *(const float2*)&wbase[(kh * 3 + kw) * 128];
#pragma unroll
          for (int ow = 0; ow < 8; ++ow) {
            float r = rr[ow + kw];
            acc[0][ow] = fmaf(r, wv.x, acc[0][ow]);
            acc[1][ow] = fmaf(r, wv.y, acc[1][ow]);
          }
        }
      }
    }
  }
  const int oh = oh0 + oh_l;
  if (oh < H2) {
#pragma unroll
    for (int o = 0; o < 2; ++o) {
      int oc = oc0 + ocg * 2 + o;
      float* dst = &outp[((size_t)b * C3 + oc) * NN + oh * 8];
      *(float4*)dst       = make_float4(acc[o][0], acc[o][1], acc[o][2], acc[o][3]);
      *(float4*)(dst + 4) = make_float4(acc[o][4], acc[o][5], acc[o][6], acc[o][7]);
    }
  }
}

// ========== fused conv5a + conv5c (3x3, cin128 -> 32+32) + BN + ReLU ==========
// grid (65, 4), block 128. Input = relu(p3a + p3b + b3) in staging.
__global__ __launch_bounds__(128) void k_c5(const float* __restrict__ p3a,
                                            const float* __restrict__ p3b,
                                            const float* __restrict__ b3,
                                            const float* __restrict__ wa,
                                            const float* __restrict__ sa5, const float* __restrict__ ba5,
                                            const float* __restrict__ ma5, const float* __restrict__ va5,
                                            const float* __restrict__ wc,
                                            const float* __restrict__ sc5, const float* __restrict__ bc5,
                                            const float* __restrict__ mc5, const float* __restrict__ vc5,
                                            float* __restrict__ f1, float* __restrict__ f2) {
  __shared__ __align__(16) float tin[8 * 10 * 12];  // 960
  __shared__ __align__(16) float twt[72 * 64];
  const int oh0 = blockIdx.x * 8;
  const int b   = blockIdx.y;
  const int tid = threadIdx.x;
  const int vocg = tid >> 3, oh_l = tid & 7;
  float acc[4][8] = {};
  for (int cc = 0; cc < 16; ++cc) {
    __syncthreads();
    for (int e = tid; e < 640; e += 128) {
      int ci = e / 80, r = e - ci * 80;
      int tr = r >> 3, c = r & 7;
      int ih = oh0 - 1 + tr;
      int cin = cc * 8 + ci;
      float v = 0.f;
      if (ih >= 0 && ih < H2) {
        size_t idx = ((size_t)b * C3 + cin) * NN + ih * 8 + c;
        v = frelu(p3a[idx] + p3b[idx] + b3[cin]);
      }
      tin[(ci * 10 + tr) * 12 + c] = v;
    }
    for (int e = tid; e < 4608; e += 128) {
      int voc_l = e & 63, t = e >> 6;
      const float* base = (voc_l < 32) ? (wa + (size_t)voc_l * 1152) : (wc + (size_t)(voc_l - 32) * 1152);
      twt[t * 64 + voc_l] = base[cc * 8 * 9 + t];
    }
    __syncthreads();
#pragma unroll 1
    for (int ci = 0; ci < 8; ++ci) {
#pragma unroll
      for (int kh = 0; kh < 3; ++kh) {
        const float* rp = &tin[(ci * 10 + oh_l + kh) * 12];
        float4 a0 = *(const float4*)rp;
        float4 a1 = *(const float4*)(rp + 4);
        float rr[10];
        rr[0] = 0.f; rr[9] = 0.f;
        rr[1] = a0.x; rr[2] = a0.y; rr[3] = a0.z; rr[4] = a0.w;
        rr[5] = a1.x; rr[6] = a1.y; rr[7] = a1.z; rr[8] = a1.w;
#pragma unroll
        for (int kw = 0; kw < 3; ++kw) {
          float4 wv = *(const float4*)&twt[(ci * 9 + kh * 3 + kw) * 64 + vocg * 4];
#pragma unroll
          for (int ow = 0; ow < 8; ++ow) {
            float r = rr[ow + kw];
            acc[0][ow] = fmaf(r, wv.x, acc[0][ow]);
            acc[1][ow] = fmaf(r, wv.y, acc[1][ow]);
            acc[2][ow] = fmaf(r, wv.z, acc[2][ow]);
            acc[3][ow] = fmaf(r, wv.w, acc[3][ow]);
          }
        }
      }
    }
  }
  const int oh = oh0 + oh_l;
  if (oh < H2) {
#pragma unroll
    for (int vv = 0; vv < 4; ++vv) {
      int voc = vocg * 4 + vv;
      bool A = voc < 32;
      int ci = voc & 31;
      float sN = A ? sa5[ci] : sc5[ci];
      float bN = A ? ba5[ci] : bc5[ci];
      float mN = A ? ma5[ci] : mc5[ci];
      float vN = A ? va5[ci] : vc5[ci];
      float inv = sN * rsqrtf(vN + 1e-5f);
      float sh  = bN - mN * inv;
      float* dst = (A ? f1 : f2) + ((size_t)b * 32 + ci) * NN + oh * 8;
      float y[8];
#pragma unroll
      for (int ow = 0; ow < 8; ++ow) y[ow] = frelu(acc[vv][ow] * inv + sh);
      *(float4*)dst       = make_float4(y[0], y[1], y[2], y[3]);
      *(float4*)(dst + 4) = make_float4(y[4], y[5], y[6], y[7]);
    }
  }
}

// ================= 1x1 convs for q, k, v =================
// grid (17, 40, 4), block 256.
__global__ __launch_bounds__(256) void k_qkv(const float* __restrict__ f1,
                                             const float* __restrict__ qw, const float* __restrict__ qbv,
                                             const float* __restrict__ kwp, const float* __restrict__ kbv,
                                             const float* __restrict__ vwp, const float* __restrict__ vbv,
                                             float* __restrict__ qo, float* __restrict__ ko,
                                             float* __restrict__ vo) {
  const int n = blockIdx.x * 256 + threadIdx.x;
  if (n >= NN) return;
  const int ocv = blockIdx.y, b = blockIdx.z;
  const float* w;
  float bias;
  float* dst;
  if (ocv < 4)      { w = qw + ocv * 32;        bias = qbv[ocv];     dst = qo + ((size_t)b * 4 + ocv) * NN; }
  else if (ocv < 8) { int o = ocv - 4; w = kwp + o * 32; bias = kbv[o]; dst = ko + ((size_t)b * 4 + o) * NN; }
  else              { int o = ocv - 8; w = vwp + o * 32; bias = vbv[o]; dst = vo + ((size_t)b * 32 + o) * NN; }
  float a = bias;
#pragma unroll
  for (int c = 0; c < 32; ++c) a = fmaf(f1[((size_t)b * 32 + c) * NN + n], w[c], a);
  dst[n] = a;
}

// ================= flash PAM attention, partial (j-split x15) =================
__device__ __forceinline__ float rmax32(const float (&p)[32]) {
  float x0 = p[0], x1 = p[1], x2 = p[2], x3 = p[3];
#pragma unroll
  for (int j = 4; j < 32; j += 4) {
    x0 = fmaxf(x0, p[j]); x1 = fmaxf(x1, p[j + 1]);
    x2 = fmaxf(x2, p[j + 2]); x3 = fmaxf(x3, p[j + 3]);
  }
  return fmaxf(fmaxf(x0, x1), fmaxf(x2, x3));
}
__device__ __forceinline__ float rsum32(const float (&p)[32]) {
  float x0 = p[0], x1 = p[1], x2 = p[2], x3 = p[3];
#pragma unroll
  for (int j = 4; j < 32; j += 4) { x0 += p[j]; x1 += p[j + 1]; x2 += p[j + 2]; x3 += p[j + 3]; }
  return (x0 + x1) + (x2 + x3);
}

// grid (17, 15, 4), block 256 (4 waves).
__global__ __launch_bounds__(256) void k_flash(const float* __restrict__ qb,
                                               const float* __restrict__ kb,
                                               const float* __restrict__ vb,
                                               float* __restrict__ accp,
                                               float* __restrict__ mlb) {
  __shared__ __align__(16) float ks[4 * 32];
  __shared__ __align__(16) float vs[32 * 32];
  const int tid = threadIdx.x;
  const int ia  = blockIdx.x * 256 + tid;
  const int sp  = blockIdx.y;
  const int b   = blockIdx.z;
  float q[4];
#pragma unroll
  for (int d = 0; d < 4; ++d)
    q[d] = (ia < NN) ? qb[((size_t)b * 4 + d) * NN + ia] : 0.f;
  float m = -1e30f, l = 0.f;
  float acc[32];
#pragma unroll
  for (int c = 0; c < 32; ++c) acc[c] = 0.f;
  const int jbeg = sp * JSPAN;
  const int jend = (jbeg + JSPAN < NN) ? jbeg + JSPAN : NN;
  const int cs = tid >> 3, j4 = (tid & 7) * 4;   // staging coords
  for (int j0 = jbeg; j0 < jend; j0 += 32) {
    const int nv = (jend - j0 < 32) ? jend - j0 : 32;
    __syncthreads();
    {
      const float* vsrc = &vb[((size_t)b * 32 + cs) * NN + j0 + j4];
      float4 v4;
      if (j4 + 4 <= nv) {
        v4 = *(const float4*)vsrc;
      } else {
        v4.x = (j4 + 0 < nv) ? vsrc[0] : 0.f;
        v4.y = (j4 + 1 < nv) ? vsrc[1] : 0.f;
        v4.z = (j4 + 2 < nv) ? vsrc[2] : 0.f;
        v4.w = (j4 + 3 < nv) ? vsrc[3] : 0.f;
      }
      *(float4*)&vs[cs * 32 + j4] = v4;
      if (tid < 32) {
        const int d = tid >> 3;
        const float* ksrc = &kb[((size_t)b * 4 + d) * NN + j0 + j4];
        float4 k4;
        if (j4 + 4 <= nv) {
          k4 = *(const float4*)ksrc;
        } else {
          k4.x = (j4 + 0 < nv) ? ksrc[0] : 0.f;
          k4.y = (j4 + 1 < nv) ? ksrc[1] : 0.f;
          k4.z = (j4 + 2 < nv) ? ksrc[2] : 0.f;
          k4.w = (j4 + 3 < nv) ? ksrc[3] : 0.f;
        }
        *(float4*)&ks[d * 32 + j4] = k4;
      }
    }
    __syncthreads();
    float p[32];
#pragma unroll
    for (int jj = 0; jj < 8; ++jj) {
      float4 k0 = *(const float4*)&ks[0 * 32 + 4 * jj];
      float4 k1 = *(const float4*)&ks[1 * 32 + 4 * jj];
      float4 k2 = *(const float4*)&ks[2 * 32 + 4 * jj];
      float4 k3 = *(const float4*)&ks[3 * 32 + 4 * jj];
      p[4 * jj + 0] = fmaf(q[0], k0.x, fmaf(q[1], k1.x, fmaf(q[2], k2.x, q[3] * k3.x)));
      p[4 * jj + 1] = fmaf(q[0], k0.y, fmaf(q[1], k1.y, fmaf(q[2], k2.y, q[3] * k3.y)));
      p[4 * jj + 2] = fmaf(q[0], k0.z, fmaf(q[1], k1.z, fmaf(q[2], k2.z, q[3] * k3.z)));
      p[4 * jj + 3] = fmaf(q[0], k0.w, fmaf(q[1], k1.w, fmaf(q[2], k2.w, q[3] * k3.w)));
    }
    if (nv < 32) {
#pragma unroll
      for (int j = 0; j < 32; ++j)
        if (j >= nv) p[j] = -1e30f;
    }
    float mn = fmaxf(m, rmax32(p));
    float f = __expf(m - mn);
    m = mn;
#pragma unroll
    for (int j = 0; j < 32; ++j) p[j] = __expf(p[j] - mn);
    l = fmaf(l, f, rsum32(p));
#pragma unroll
    for (int c = 0; c < 32; ++c) acc[c] *= f;
#pragma unroll
    for (int jj = 0; jj < 8; ++jj) {
      float4 p4 = make_float4(p[4 * jj], p[4 * jj + 1], p[4 * jj + 2], p[4 * jj + 3]);
#pragma unroll
      for (int c = 0; c < 32; ++c) {
        float4 vv = *(const float4*)&vs[c * 32 + 4 * jj];
        acc[c] = fmaf(p4.x, vv.x, fmaf(p4.y, vv.y, fmaf(p4.z, vv.z, fmaf(p4.w, vv.w, acc[c]))));
      }
    }
  }
  if (ia < NN) {
    const size_t sb4 = (size_t)(sp * 4 + b);
#pragma unroll
    for (int c = 0; c < 32; ++c)
      accp[(sb4 * 32 + c) * NPAD + ia] = acc[c];
    mlb[(sb4 * 2 + 0) * NPAD + ia] = m;
    mlb[(sb4 * 2 + 1) * NPAD + ia] = l;
  }
}

// ================= combine flash partials -> sa = gamma*attn@v + feat1 ============
// grid (17, 32, 4), block 256.
__global__ __launch_bounds__(256) void k_combine(const float* __restrict__ accp,
                                                 const float* __restrict__ mlb,
                                                 const float* __restrict__ f1,
                                                 const float* __restrict__ gamma,
                                                 float* __restrict__ sa) {
  const int n = blockIdx.x * 256 + threadIdx.x;
  if (n >= NN) return;
  const int c = blockIdx.y, b = blockIdx.z;
  float m[NSPLIT], l[NSPLIT];
#pragma unroll
  for (int s = 0; s < NSPLIT; ++s) {
    m[s] = mlb[((size_t)(s * 4 + b) * 2 + 0) * NPAD + n];
    l[s] = mlb[((size_t)(s * 4 + b) * 2 + 1) * NPAD + n];
  }
  float ms = m[0];
#pragma unroll
  for (int s = 1; s < NSPLIT; ++s) ms = fmaxf(ms, m[s]);
  float den = 0.f, num = 0.f;
#pragma unroll
  for (int s = 0; s < NSPLIT; ++s) {
    float w = __expf(m[s] - ms);
    den = fmaf(l[s], w, den);
    num = fmaf(w, accp[((size_t)(s * 4 + b) * 32 + c) * NPAD + n], num);
  }
  size_t o = ((size_t)b * 32 + c) * NN + n;
  sa[o] = gamma[0] * num / den + f1[o];
}

// ================= CAM: energy (atomic partials) ==============================
__global__ __launch_bounds__(256) void k_zero(float* __restrict__ p) {
  int i = blockIdx.x * 256 + threadIdx.x;
  if (i < 4096) p[i] = 0.f;
}

// grid (17, 4), block 256.
__global__ __launch_bounds__(256) void k_energy(const float* __restrict__ f2,
                                                float* __restrict__ energy) {
  __shared__ float fs[32 * 257];
  const int n0 = blockIdx.x * 256, b = blockIdx.y, tid = threadIdx.x;
  for (int e = tid; e < 32 * 256; e += 256) {
    int c = e >> 8, nl = e & 255;
    int n = n0 + nl;
    fs[c * 257 + nl] = (n < NN) ? f2[((size_t)b * 32 + c) * NN + n] : 0.f;
  }
  __syncthreads();
  const int cg = tid >> 4, dg = tid & 15;
  const int c0 = cg * 2, d0 = dg * 2;
  float e00 = 0.f, e01 = 0.f, e10 = 0.f, e11 = 0.f;
  for (int t = 0; t < 256; ++t) {
    float a0 = fs[c0 * 257 + t], a1 = fs[(c0 + 1) * 257 + t];
    float b0 = fs[d0 * 257 + t], b1 = fs[(d0 + 1) * 257 + t];
    e00 = fmaf(a0, b0, e00); e01 = fmaf(a0, b1, e01);
    e10 = fmaf(a1, b0, e10); e11 = fmaf(a1, b1, e11);
  }
  float* eb = energy + b * 1024;
  atomicAdd(&eb[c0 * 32 + d0], e00);
  atomicAdd(&eb[c0 * 32 + d0 + 1], e01);
  atomicAdd(&eb[(c0 + 1) * 32 + d0], e10);
  atomicAdd(&eb[(c0 + 1) * 32 + d0 + 1], e11);
}

// ======== CAM apply: cattn = softmax(maxE - E) rows; sc = g*cattn@f2 + f2 ========
// grid (65, 4), block 64.
__global__ __launch_bounds__(64) void k_cam(const float* __restrict__ f2,
                                            const float* __restrict__ energy,
                                            const float* __restrict__ gamma,
                                            float* __restrict__ sc) {
  __shared__ __align__(16) float cat[32 * 32];
  const int lane = threadIdx.x, b = blockIdx.y;
  const int n = blockIdx.x * 64 + lane;
  if (lane < 32) {
    const float* eb = energy + b * 1024 + lane * 32;
    float e[32];
#pragma unroll
    for (int d = 0; d < 32; ++d) e[d] = eb[d];
    float mn = e[0];
#pragma unroll
    for (int d = 1; d < 32; ++d) mn = fminf(mn, e[d]);
    float w[32];
    float sum = 0.f;
#pragma unroll
    for (int d = 0; d < 32; ++d) { w[d] = __expf(mn - e[d]); sum += w[d]; }
    float inv = 1.f / sum;
#pragma unroll
    for (int d = 0; d < 32; ++d) cat[lane * 32 + d] = w[d] * inv;
  }
  __syncthreads();
  const bool ok = n < NN;
  float f[32];
#pragma unroll
  for (int c = 0; c < 32; ++c) f[c] = ok ? f2[((size_t)b * 32 + c) * NN + n] : 0.f;
  const float g = gamma[0];
#pragma unroll
  for (int c = 0; c < 32; ++c) {
    float a = 0.f;
#pragma unroll
    for (int k4 = 0; k4 < 8; ++k4) {
      float4 cw = *(const float4*)&cat[c * 32 + 4 * k4];
      a = fmaf(cw.x, f[4 * k4], fmaf(cw.y, f[4 * k4 + 1], fmaf(cw.z, f[4 * k4 + 2], fmaf(cw.w, f[4 * k4 + 3], a))));
    }
    if (ok) sc[((size_t)b * 32 + c) * NN + n] = g * a + f[c];
  }
}

// ======== fused c51(sa)+BN+ReLU, c52(sc)+BN+ReLU, sum, conv8 1x1 -> out ========
// grid (65, 4), block 128.
__global__ __launch_bounds__(128) void k_final(const float* __restrict__ sa,
                                               const float* __restrict__ sc,
                                               const float* __restrict__ w51,
                                               const float* __restrict__ s51, const float* __restrict__ b51,
                                               const float* __restrict__ m51, const float* __restrict__ v51,
                                               const float* __restrict__ w52,
                                               const float* __restrict__ s52, const float* __restrict__ b52,
                                               const float* __restrict__ m52, const float* __restrict__ v52,
                                               const float* __restrict__ w8, const float* __restrict__ b8,
                                               float* __restrict__ out) {
  __shared__ __align__(16) float tin[2 * 8 * 10 * 12];  // 1920
  __shared__ __align__(16) float twt[72 * 64];          // 4608
  __shared__ float tmid[64 * 65];
  const int oh0 = blockIdx.x * 8;
  const int b   = blockIdx.y;
  const int tid = threadIdx.x;
  const int vocg = tid >> 3, oh_l = tid & 7;
  float acc[4][8] = {};
  for (int cc = 0; cc < 4; ++cc) {
    __syncthreads();
    for (int e = tid; e < 1280; e += 128) {
      int which = (e >= 640) ? 1 : 0;
      int r1 = e - which * 640;
      int ci = r1 / 80, r2 = r1 - ci * 80;
      int tr = r2 >> 3, c = r2 & 7;
      int ih = oh0 - 1 + tr;
      int cin = cc * 8 + ci;
      const float* src = which ? sc : sa;
      float v = 0.f;
      if (ih >= 0 && ih < H2) v = src[((size_t)b * 32 + cin) * NN + ih * 8 + c];
      tin[which * 960 + (ci * 10 + tr) * 12 + c] = v;
    }
    for (int e = tid; e < 4608; e += 128) {
      int voc_l = e & 63, t = e >> 6;
      const float* base = (voc_l < 32) ? (w51 + voc_l * 288) : (w52 + (voc_l - 32) * 288);
      twt[t * 64 + voc_l] = base[cc * 8 * 9 + t];
    }
    __syncthreads();
    const float* tbase = tin + (vocg < 8 ? 0 : 960);
#pragma unroll 1
    for (int ci = 0; ci < 8; ++ci) {
#pragma unroll
      for (int kh = 0; kh < 3; ++kh) {
        const float* rp = tbase + (ci * 10 + oh_l + kh) * 12;
        float4 a0 = *(const float4*)rp;
        float4 a1 = *(const float4*)(rp + 4);
        float rr[10];
        rr[0] = 0.f; rr[9] = 0.f;
        rr[1] = a0.x; rr[2] = a0.y; rr[3] = a0.z; rr[4] = a0.w;
        rr[5] = a1.x; rr[6] = a1.y; rr[7] = a1.z; rr[8] = a1.w;
#pragma unroll
        for (int kw = 0; kw < 3; ++kw) {
          float4 wv = *(const float4*)&twt[(ci * 9 + kh * 3 + kw) * 64 + vocg * 4];
#pragma unroll
          for (int ow = 0; ow < 8; ++ow) {
            float r = rr[ow + kw];
            acc[0][ow] = fmaf(r, wv.x, acc[0][ow]);
            acc[1][ow] = fmaf(r, wv.y, acc[1][ow]);
            acc[2][ow] = fmaf(r, wv.z, acc[2][ow]);
            acc[3][ow] = fmaf(r, wv.w, acc[3][ow]);
          }
        }
      }
    }
  }
  {
    float inv[4], sh[4];
#pragma unroll
    for (int vv = 0; vv < 4; ++vv) {
      int voc = vocg * 4 + vv;
      bool A = voc < 32;
      int ci = voc & 31;
      float sN = A ? s51[ci] : s52[ci];
      float bN = A ? b51[ci] : b52[ci];
      float mN = A ? m51[ci] : m52[ci];
      float vN = A ? v51[ci] : v52[ci];
      inv[vv] = sN * rsqrtf(vN + 1e-5f);
      sh[vv] = bN - mN * inv[vv];
    }
#pragma unroll
    for (int ow = 0; ow < 8; ++ow) {
      int pos = oh_l * 8 + ow;
#pragma unroll
      for (int vv = 0; vv < 4; ++vv) {
        float y = acc[vv][ow] * inv[vv] + sh[vv];
        tmid[pos * 65 + vocg * 4 + vv] = frelu(y);
      }
    }
  }
  __syncthreads();
  {
    const int o = tid >> 6, pos = tid & 63;
    const int oh = oh0 + (pos >> 3), ow = pos & 7;
    float a = b8[o];
    const float* wrow = w8 + o * 32;
#pragma unroll
    for (int c = 0; c < 32; ++c)
      a = fmaf(tmid[pos * 65 + c] + tmid[pos * 65 + 32 + c], wrow[c], a);
    if (oh < H2) out[((size_t)b * 2 + o) * NN + oh * 8 + ow] = a;
  }
}

// =========================== launcher ===========================
extern "C" void kernel_launch(void* const* d_in, const int* in_sizes, int n_in,
                              void* d_out, int out_size, void* d_ws, size_t ws_size,
                              hipStream_t stream) {
  (void)in_sizes; (void)n_in; (void)out_size; (void)ws_size;
  const float* x      = (const float*)d_in[0];
  const float* w1     = (const float*)d_in[1];
  const float* b1     = (const float*)d_in[2];
  const float* w2     = (const float*)d_in[3];
  const float* b2     = (const float*)d_in[4];
  const float* w3     = (const float*)d_in[5];
  const float* b3     = (const float*)d_in[6];
  const float* c5a_w  = (const float*)d_in[7];
  const float* bn5a_s = (const float*)d_in[8];
  const float* bn5a_b = (const float*)d_in[9];
  const float* bn5a_m = (const float*)d_in[10];
  const float* bn5a_v = (const float*)d_in[11];
  const float* c5c_w  = (const float*)d_in[12];
  const float* bn5c_s = (const float*)d_in[13];
  const float* bn5c_b = (const float*)d_in[14];
  const float* bn5c_m = (const float*)d_in[15];
  const float* bn5c_v = (const float*)d_in[16];
  const float* c51_w  = (const float*)d_in[17];
  const float* bn51_s = (const float*)d_in[18];
  const float* bn51_b = (const float*)d_in[19];
  const float* bn51_m = (const float*)d_in[20];
  const float* bn51_v = (const float*)d_in[21];
  const float* c52_w  = (const float*)d_in[22];
  const float* bn52_s = (const float*)d_in[23];
  const float* bn52_b = (const float*)d_in[24];
  const float* bn52_m = (const float*)d_in[25];
  const float* bn52_v = (const float*)d_in[26];
  const float* pam_qw = (const float*)d_in[27];
  const float* pam_qb = (const float*)d_in[28];
  const float* pam_kw = (const float*)d_in[29];
  const float* pam_kb = (const float*)d_in[30];
  const float* pam_vw = (const float*)d_in[31];
  const float* pam_vb = (const float*)d_in[32];
  const float* pgamma = (const float*)d_in[33];
  const float* cgamma = (const float*)d_in[34];
  const float* c8_w   = (const float*)d_in[35];
  const float* c8_b   = (const float*)d_in[36];

  float* W    = (float*)d_ws;
  float* h1   = W + OFF_H1;
  float* p2   = W + OFF_P2;
  float* p3a  = W + OFF_P3A;
  float* p3b  = W + OFF_P3B;
  float* f1   = W + OFF_F1;
  float* f2   = W + OFF_F2;
  float* qbuf = W + OFF_Q;
  float* kbuf = W + OFF_K;
  float* vbuf = W + OFF_V;
  float* sab  = W + OFF_SA;
  float* scb  = W + OFF_SC;
  float* accp = W + OFF_ACCP;
  float* mlb  = W + OFF_ML;
  float* enb  = W + OFF_EN;
  float* w2T  = W + OFF_W2T;
  float* w3T  = W + OFF_W3T;
  float* outp = (float*)d_out;

  k_wtrans<<<dim3(3200), 256, 0, stream>>>(w2, w3, w2T, w3T);
  k_conv1<<<dim3(65, 16, 4), 256, 0, stream>>>(x, w1, b1, h1);
  k_conv2<<<dim3(65, 8, 4), 128, 0, stream>>>(h1, w2T, b2, p2);
  k_conv3<<<dim3(65, 8, 4), 128, 0, stream>>>(p2, w3T, p3a, p3b);
  k_c5<<<dim3(65, 4), 128, 0, stream>>>(p3a, p3b, b3,
                                        c5a_w, bn5a_s, bn5a_b, bn5a_m, bn5a_v,
                                        c5c_w, bn5c_s, bn5c_b, bn5c_m, bn5c_v,
                                        f1, f2);
  k_qkv<<<dim3(17, 40, 4), 256, 0, stream>>>(f1, pam_qw, pam_qb, pam_kw, pam_kb,
                                             pam_vw, pam_vb, qbuf, kbuf, vbuf);
  k_zero<<<dim3(16), 256, 0, stream>>>(enb);
  k_flash<<<dim3(17, NSPLIT, 4), 256, 0, stream>>>(qbuf, kbuf, vbuf, accp, mlb);
  k_energy<<<dim3(17, 4), 256, 0, stream>>>(f2, enb);
  k_combine<<<dim3(17, 32, 4), 256, 0, stream>>>(accp, mlb, f1, pgamma, sab);
  k_cam<<<dim3(65, 4), 64, 0, stream>>>(f2, enb, cgamma, scb);
  k_final<<<dim3(65, 4), 128, 0, stream>>>(sab, scb,
                                           c51_w, bn51_s, bn51_b, bn51_m, bn51_v,
                                           c52_w, bn52_s, bn52_b, bn52_m, bn52_v,
                                           c8_w, c8_b, outp);
}

// Round 11
// 1254.798 us; speedup vs baseline: 1.2597x; 1.2459x over previous
//
#include <hip/hip_runtime.h>
#include <cstddef>

// ---------------- problem dims ----------------
constexpr int BB   = 4;
constexpr int LX   = 126975;
constexpr int H0   = 4096, W0 = 61;          // c_in spatial
constexpr int C1   = 128, H1 = 1025, W1 = 16;
constexpr int C2   = 256, H2 = 513,  W2 = 8;
constexpr int C3   = 128;
constexpr int NN   = H2 * W2;                // 4104
constexpr int NSPLIT = 15;                   // attention j-splits
constexpr int JSPAN  = 288;                  // 32-aligned; 15*288 >= 4104
constexpr int NPAD   = 4104;                 // partial-row stride (16B-aligned)

// ---------------- workspace layout (float offsets), lifetime-overlapped ----
constexpr size_t SZ_H1    = (size_t)BB * C1 * H1 * W1;        // 8,396,800
constexpr size_t SZ_P2    = (size_t)BB * C2 * NN;             // 4,202,496
constexpr size_t SZ_P3    = (size_t)BB * C3 * NN;             // 2,101,248
constexpr size_t SZ_F     = (size_t)BB * 32 * NN;             //   525,312
constexpr size_t SZ_QK    = (size_t)BB * 4 * NN;              //    65,664
constexpr size_t SZ_ACCP  = (size_t)NSPLIT * BB * 32 * NPAD;  // 7,879,680
constexpr size_t SZ_ML    = (size_t)NSPLIT * BB * 2 * NPAD;   //   492,480

// Region A [0, 8,396,800): h1c hi/lo bf16 (conv1->conv2, same footprint as
//   old fp32 h1); p3a/p3b (conv3->c5); then accp/ml (flash->combine).
constexpr size_t OFF_H1CH = 0;                  // 4,198,400 floats of ushort
constexpr size_t OFF_H1CL = 4198400;
constexpr size_t OFF_P3A  = 0;
constexpr size_t OFF_P3B  = SZ_P3;              // ends 4,202,496 < 8,396,800
constexpr size_t OFF_ACCP = 0;                  // after c5 (p3a/b dead)
constexpr size_t OFF_ML   = OFF_ACCP + SZ_ACCP; // ends 8,372,160 < 8,396,800
constexpr size_t RB       = SZ_H1;              // 8,396,800
constexpr size_t OFF_P2   = RB;
constexpr size_t OFF_F1   = RB;                 // reuses p2 (dead after conv3)
constexpr size_t OFF_F2   = OFF_F1 + SZ_F;
constexpr size_t OFF_Q    = OFF_F2 + SZ_F;
constexpr size_t OFF_K    = OFF_Q  + SZ_QK;
constexpr size_t OFF_V    = OFF_K  + SZ_QK;
constexpr size_t OFF_SA   = OFF_V  + SZ_F;
constexpr size_t OFF_SC   = OFF_SA + SZ_F;
constexpr size_t OFF_EN   = RB + SZ_P2;         // 4096 floats
constexpr size_t OFF_W2B  = OFF_EN + 4096;      // 819,200 floats: w2b hi|lo (ushort)
constexpr size_t OFF_W3T  = OFF_W2B + 819200;   // 2304*128 = 294,912
// total = 13,717,504 floats = 54.9 MB (unchanged from round 8/9)

__device__ __forceinline__ float frelu(float x) { return x > 0.f ? x : 0.f; }
__device__ __forceinline__ ushort f2bf(float v) {
  unsigned u = __float_as_uint(v);
  return (ushort)((u + 0x7FFF + ((u >> 16) & 1)) >> 16);
}

typedef __attribute__((ext_vector_type(8))) short bf8;
typedef __attribute__((ext_vector_type(4))) float f32x4;

// ========= w2 -> bf16 hi/lo, layout [(kh*5+kw)][oc][cin] (cin-minor) =========
// grid (256), block 128.
__global__ __launch_bounds__(128) void k_wcvt(const float* __restrict__ w2,
                                              ushort* __restrict__ w2bh,
                                              ushort* __restrict__ w2bl) {
  const int oc = blockIdx.x, cin = threadIdx.x;
  const float* src = w2 + (size_t)oc * 3200 + cin * 25;
#pragma unroll 1
  for (int p = 0; p < 25; ++p) {
    float v = src[p];
    ushort h = f2bf(v);
    float hf = __uint_as_float(((unsigned)h) << 16);
    ushort lo = f2bf(v - hf);
    size_t o = ((size_t)p * 256 + oc) * 128 + cin;
    w2bh[o] = h;
    w2bl[o] = lo;
  }
}

// ========= w3 transpose (fp32, oc-minor) for conv3 =========
// grid (2304), block 128.
__global__ __launch_bounds__(128) void k_w3t(const float* __restrict__ w3,
                                             float* __restrict__ w3T) {
  const int k = blockIdx.x, oc = threadIdx.x;
  w3T[(size_t)k * 128 + oc] = w3[(size_t)oc * 2304 + k];
}

// ================= conv1: 8x8 s4 p4, cin=1, 128 oc, +bias+relu ================
// grid (65, 16, 4), block 256.  Output: channel-minor bf16 hi/lo pair
// h1c[b][ih][iw][cin] (16B/thread stores) -- the MFMA-conv2 A operand.
__global__ __launch_bounds__(256) void k_conv1(const float* __restrict__ x,
                                               const float* __restrict__ w1,
                                               const float* __restrict__ b1,
                                               ushort* __restrict__ h1ch,
                                               ushort* __restrict__ h1cl) {
  __shared__ __align__(16) float tile[68 * 68];
  const int oh0 = blockIdx.x * 16;
  const int oc0 = blockIdx.y * 8;
  const int b   = blockIdx.z;
  const int tid = threadIdx.x;
  const int ih0 = oh0 * 4 - 4;
  for (int e = tid; e < 68 * 68; e += 256) {
    int row = e / 68, col = e - row * 68;
    int ih = ih0 + row, iw = col - 4;
    float v = 0.f;
    if (ih >= 0 && ih < H0 && iw >= 0 && iw < W0) {
      int l   = ih * W0 + iw;
      int pos = (l >> 12) * 2048 + (l & 4095);
      if (pos < LX) v = x[(size_t)b * LX + pos];
    }
    tile[e] = v;
  }
  __syncthreads();
  const int oh_l = tid >> 4, ow = tid & 15;
  float acc[8];
#pragma unroll
  for (int o = 0; o < 8; ++o) acc[o] = 0.f;
#pragma unroll
  for (int kh = 0; kh < 8; ++kh) {
    const float* rp = &tile[(4 * oh_l + kh) * 68 + 4 * ow];
    float4 a0 = *(const float4*)rp;
    float4 a1 = *(const float4*)(rp + 4);
    float r[8] = {a0.x, a0.y, a0.z, a0.w, a1.x, a1.y, a1.z, a1.w};
#pragma unroll
    for (int kw = 0; kw < 8; ++kw) {
#pragma unroll
      for (int o = 0; o < 8; ++o)
        acc[o] = fmaf(r[kw], w1[(oc0 + o) * 64 + kh * 8 + kw], acc[o]);
    }
  }
  const int oh = oh0 + oh_l;
  if (oh < H1) {
    unsigned hw[4], lw[4];
#pragma unroll
    for (int o2 = 0; o2 < 4; ++o2) {
      float v0 = frelu(acc[2 * o2]     + b1[oc0 + 2 * o2]);
      float v1 = frelu(acc[2 * o2 + 1] + b1[oc0 + 2 * o2 + 1]);
      ushort h0 = f2bf(v0), h1u = f2bf(v1);
      hw[o2] = (unsigned)h0 | ((unsigned)h1u << 16);
      float l0 = v0 - __uint_as_float(((unsigned)h0) << 16);
      float l1 = v1 - __uint_as_float(((unsigned)h1u) << 16);
      lw[o2] = (unsigned)f2bf(l0) | ((unsigned)f2bf(l1) << 16);
    }
    size_t base = (((size_t)b * H1 + oh) * 16 + ow) * 128 + oc0;
    *(uint4*)(h1ch + base) = make_uint4(hw[0], hw[1], hw[2], hw[3]);
    *(uint4*)(h1cl + base) = make_uint4(lw[0], lw[1], lw[2], lw[3]);
  }
}

// ========= conv2: implicit-GEMM MFMA 16x16x32 bf16, split-bf16 (3 MFMA) =========
// GEMM per batch: C[4104 m][256 oc] += A[m][cin] @ W[cin][oc], accumulated over
// the 25 (kh,kw) shifts; K = 128 cin as 4 chunks of 32.  No LDS: A-frag is a
// per-lane 16B load from channel-minor h1c (row=lane&15, k=8*(lane>>4)+j);
// B-frag the same from [p][oc][cin] w2b.  Wave = M32 x N64 (2 m-frags, 4 n-frags,
// 24 MFMA per K-step); block 256 = 4 waves splitting N=256.
// grid (129, 4) -- 516 blocks, ~2 waves/SIMD, MFMA-dense.
__global__ __launch_bounds__(256) void k_conv2(const ushort* __restrict__ h1ch,
                                               const ushort* __restrict__ h1cl,
                                               const ushort* __restrict__ w2bh,
                                               const ushort* __restrict__ w2bl,
                                               const float* __restrict__ b2,
                                               float* __restrict__ p2) {
  const int tid  = threadIdx.x;
  const int lane = tid & 63, wid = tid >> 6;
  const int row  = lane & 15, kg = lane >> 4;
  const int b    = blockIdx.y;
  const int mbase = blockIdx.x * 32;
  int oh[2], ow[2];
#pragma unroll
  for (int mi = 0; mi < 2; ++mi) {
    int mt = mbase + mi * 16 + row;
    oh[mi] = mt >> 3;
    ow[mi] = mt & 7;
  }
  const size_t bconst = (size_t)(wid * 64 + row) * 128 + 8 * kg;
  const bf8 z = {0, 0, 0, 0, 0, 0, 0, 0};
  f32x4 acc[2][4];
#pragma unroll
  for (int mi = 0; mi < 2; ++mi)
#pragma unroll
    for (int ns = 0; ns < 4; ++ns) acc[mi][ns] = (f32x4){0.f, 0.f, 0.f, 0.f};
#pragma unroll 1
  for (int kh = 0; kh < 5; ++kh) {
#pragma unroll 1
    for (int kw = 0; kw < 5; ++kw) {
      const int p = kh * 5 + kw;
      const size_t bp = (size_t)p * 32768 + bconst;
      bool ok[2];
      size_t ab[2];
#pragma unroll
      for (int mi = 0; mi < 2; ++mi) {
        int ih = 2 * oh[mi] + kh - 2;
        int iw = 2 * ow[mi] + kw - 2;
        ok[mi] = ((unsigned)ih < 1025u) && ((unsigned)iw < 16u);
        ab[mi] = ok[mi] ? ((((size_t)b * 1025 + ih) * 16 + iw) * 128 + 8 * kg) : 0;
      }
#pragma unroll
      for (int cc = 0; cc < 4; ++cc) {
        bf8 ah[2], al[2];
#pragma unroll
        for (int mi = 0; mi < 2; ++mi) {
          bf8 hv = *(const bf8*)(h1ch + ab[mi] + cc * 32);
          bf8 lv = *(const bf8*)(h1cl + ab[mi] + cc * 32);
          ah[mi] = ok[mi] ? hv : z;
          al[mi] = ok[mi] ? lv : z;
        }
#pragma unroll
        for (int ns = 0; ns < 4; ++ns) {
          const size_t bo = bp + (size_t)ns * 2048 + cc * 32;
          bf8 bh = *(const bf8*)(w2bh + bo);
          bf8 bl = *(const bf8*)(w2bl + bo);
#pragma unroll
          for (int mi = 0; mi < 2; ++mi) {
            acc[mi][ns] = __builtin_amdgcn_mfma_f32_16x16x32_bf16(ah[mi], bh, acc[mi][ns], 0, 0, 0);
            acc[mi][ns] = __builtin_amdgcn_mfma_f32_16x16x32_bf16(ah[mi], bl, acc[mi][ns], 0, 0, 0);
            acc[mi][ns] = __builtin_amdgcn_mfma_f32_16x16x32_bf16(al[mi], bh, acc[mi][ns], 0, 0, 0);
          }
        }
      }
    }
  }
  // C layout (m89-verified): col = lane&15 (oc), row = (lane>>4)*4 + reg (m).
#pragma unroll
  for (int mi = 0; mi < 2; ++mi) {
    const int m0 = mbase + mi * 16 + kg * 4;
    if (m0 < NN) {
#pragma unroll
      for (int ns = 0; ns < 4; ++ns) {
        const int oc = wid * 64 + ns * 16 + row;
        const float bo = b2[oc];
        float* dst = &p2[((size_t)b * C2 + oc) * NN + m0];
        *(float4*)dst = make_float4(frelu(acc[mi][ns][0] + bo), frelu(acc[mi][ns][1] + bo),
                                    frelu(acc[mi][ns][2] + bo), frelu(acc[mi][ns][3] + bo));
      }
    }
  }
}

// ================= conv3: 3x3 s1 p1, cin-split 2x128, raw partials ============
// grid (65, 8, 4): by = oc_chunk(4: 32 oc) | half<<2.  block 128: 2oc x 8ow.
__global__ __launch_bounds__(128) void k_conv3(const float* __restrict__ p2,
                                               const float* __restrict__ w3T,
                                               float* __restrict__ p3a,
                                               float* __restrict__ p3b) {
  __shared__ __align__(16) float tin[8 * 10 * 12];   // 960
  const int oh0  = blockIdx.x * 8;
  const int oc0  = (blockIdx.y & 3) * 32;
  const int half = blockIdx.y >> 2;
  const int b    = blockIdx.z;
  const int tid  = threadIdx.x;
  const int oh_l = tid & 7, ocg = tid >> 3;
  float acc[2][8] = {};
  float* outp = half ? p3b : p3a;
  for (int cc = 0; cc < 16; ++cc) {
    __syncthreads();
    for (int e = tid; e < 640; e += 128) {
      int ci = e / 80, r = e - ci * 80;
      int tr = r >> 3, c = r & 7;
      int ih = oh0 - 1 + tr;
      int cin = half * 128 + cc * 8 + ci;
      float v = 0.f;
      if (ih >= 0 && ih < H2) v = p2[((size_t)b * C2 + cin) * NN + ih * 8 + c];
      tin[(ci * 10 + tr) * 12 + c] = v;
    }
    __syncthreads();
#pragma unroll 1
    for (int ci = 0; ci < 8; ++ci) {
      const float* wbase = &w3T[(size_t)((half * 128 + cc * 8 + ci) * 9) * 128 + oc0 + ocg * 2];
#pragma unroll
      for (int kh = 0; kh < 3; ++kh) {
        const float* rp = &tin[(ci * 10 + oh_l + kh) * 12];
        float4 a0 = *(const float4*)rp;
        float4 a1 = *(const float4*)(rp + 4);
        float rr[10];
        rr[0] = 0.f; rr[9] = 0.f;
        rr[1] = a0.x; rr[2] = a0.y; rr[3] = a0.z; rr[4] = a0.w;
        rr[5] = a1.x; rr[6] = a1.y; rr[7] = a1.z; rr[8] = a1.w;
#pragma unroll
        for (int kw = 0; kw < 3; ++kw) {
          float2 wv = *(const float2*)&wbase[(kh * 3 + kw) * 128];
#pragma unroll
          for (int ow = 0; ow < 8; ++ow) {
            float r = rr[ow + kw];
            acc[0][ow] = fmaf(r, wv.x, acc[0][ow]);
            acc[1][ow] = fmaf(r, wv.y, acc[1][ow]);
          }
        }
      }
    }
  }
  const int oh = oh0 + oh_l;
  if (oh < H2) {
#pragma unroll
    for (int o = 0; o < 2; ++o) {
      int oc = oc0 + ocg * 2 + o;
      float* dst = &outp[((size_t)b * C3 + oc) * NN + oh * 8];
      *(float4*)dst       = make_float4(acc[o][0], acc[o][1], acc[o][2], acc[o][3]);
      *(float4*)(dst + 4) = make_float4(acc[o][4], acc[o][5], acc[o][6], acc[o][7]);
    }
  }
}

// ========== fused conv5a + conv5c (3x3, cin128 -> 32+32) + BN + ReLU ==========
// grid (65, 4), block 128. Input = relu(p3a + p3b + b3) in staging.
__global__ __launch_bounds__(128) void k_c5(const float* __restrict__ p3a,
                                            const float* __restrict__ p3b,
                                            const float* __restrict__ b3,
                                            const float* __restrict__ wa,
                                            const float* __restrict__ sa5, const float* __restrict__ ba5,
                                            const float* __restrict__ ma5, const float* __restrict__ va5,
                                            const float* __restrict__ wc,
                                            const float* __restrict__ sc5, const float* __restrict__ bc5,
                                            const float* __restrict__ mc5, const float* __restrict__ vc5,
                                            float* __restrict__ f1, float* __restrict__ f2) {
  __shared__ __align__(16) float tin[8 * 10 * 12];  // 960
  __shared__ __align__(16) float twt[72 * 64];
  const int oh0 = blockIdx.x * 8;
  const int b   = blockIdx.y;
  const int tid = threadIdx.x;
  const int vocg = tid >> 3, oh_l = tid & 7;
  float acc[4][8] = {};
  for (int cc = 0; cc < 16; ++cc) {
    __syncthreads();
    for (int e = tid; e < 640; e += 128) {
      int ci = e / 80, r = e - ci * 80;
      int tr = r >> 3, c = r & 7;
      int ih = oh0 - 1 + tr;
      int cin = cc * 8 + ci;
      float v = 0.f;
      if (ih >= 0 && ih < H2) {
        size_t idx = ((size_t)b * C3 + cin) * NN + ih * 8 + c;
        v = frelu(p3a[idx] + p3b[idx] + b3[cin]);
      }
      tin[(ci * 10 + tr) * 12 + c] = v;
    }
    for (int e = tid; e < 4608; e += 128) {
      int voc_l = e & 63, t = e >> 6;
      const float* base = (voc_l < 32) ? (wa + (size_t)voc_l * 1152) : (wc + (size_t)(voc_l - 32) * 1152);
      twt[t * 64 + voc_l] = base[cc * 8 * 9 + t];
    }
    __syncthreads();
#pragma unroll 1
    for (int ci = 0; ci < 8; ++ci) {
#pragma unroll
      for (int kh = 0; kh < 3; ++kh) {
        const float* rp = &tin[(ci * 10 + oh_l + kh) * 12];
        float4 a0 = *(const float4*)rp;
        float4 a1 = *(const float4*)(rp + 4);
        float rr[10];
        rr[0] = 0.f; rr[9] = 0.f;
        rr[1] = a0.x; rr[2] = a0.y; rr[3] = a0.z; rr[4] = a0.w;
        rr[5] = a1.x; rr[6] = a1.y; rr[7] = a1.z; rr[8] = a1.w;
#pragma unroll
        for (int kw = 0; kw < 3; ++kw) {
          float4 wv = *(const float4*)&twt[(ci * 9 + kh * 3 + kw) * 64 + vocg * 4];
#pragma unroll
          for (int ow = 0; ow < 8; ++ow) {
            float r = rr[ow + kw];
            acc[0][ow] = fmaf(r, wv.x, acc[0][ow]);
            acc[1][ow] = fmaf(r, wv.y, acc[1][ow]);
            acc[2][ow] = fmaf(r, wv.z, acc[2][ow]);
            acc[3][ow] = fmaf(r, wv.w, acc[3][ow]);
          }
        }
      }
    }
  }
  const int oh = oh0 + oh_l;
  if (oh < H2) {
#pragma unroll
    for (int vv = 0; vv < 4; ++vv) {
      int voc = vocg * 4 + vv;
      bool A = voc < 32;
      int ci = voc & 31;
      float sN = A ? sa5[ci] : sc5[ci];
      float bN = A ? ba5[ci] : bc5[ci];
      float mN = A ? ma5[ci] : mc5[ci];
      float vN = A ? va5[ci] : vc5[ci];
      float inv = sN * rsqrtf(vN + 1e-5f);
      float sh  = bN - mN * inv;
      float* dst = (A ? f1 : f2) + ((size_t)b * 32 + ci) * NN + oh * 8;
      float y[8];
#pragma unroll
      for (int ow = 0; ow < 8; ++ow) y[ow] = frelu(acc[vv][ow] * inv + sh);
      *(float4*)dst       = make_float4(y[0], y[1], y[2], y[3]);
      *(float4*)(dst + 4) = make_float4(y[4], y[5], y[6], y[7]);
    }
  }
}

// ================= 1x1 convs for q, k, v =================
// grid (17, 40, 4), block 256.
__global__ __launch_bounds__(256) void k_qkv(const float* __restrict__ f1,
                                             const float* __restrict__ qw, const float* __restrict__ qbv,
                                             const float* __restrict__ kwp, const float* __restrict__ kbv,
                                             const float* __restrict__ vwp, const float* __restrict__ vbv,
                                             float* __restrict__ qo, float* __restrict__ ko,
                                             float* __restrict__ vo) {
  const int n = blockIdx.x * 256 + threadIdx.x;
  if (n >= NN) return;
  const int ocv = blockIdx.y, b = blockIdx.z;
  const float* w;
  float bias;
  float* dst;
  if (ocv < 4)      { w = qw + ocv * 32;        bias = qbv[ocv];     dst = qo + ((size_t)b * 4 + ocv) * NN; }
  else if (ocv < 8) { int o = ocv - 4; w = kwp + o * 32; bias = kbv[o]; dst = ko + ((size_t)b * 4 + o) * NN; }
  else              { int o = ocv - 8; w = vwp + o * 32; bias = vbv[o]; dst = vo + ((size_t)b * 32 + o) * NN; }
  float a = bias;
#pragma unroll
  for (int c = 0; c < 32; ++c) a = fmaf(f1[((size_t)b * 32 + c) * NN + n], w[c], a);
  dst[n] = a;
}

// ================= flash PAM attention, partial (j-split x15) =================
__device__ __forceinline__ float rmax32(const float (&p)[32]) {
  float x0 = p[0], x1 = p[1], x2 = p[2], x3 = p[3];
#pragma unroll
  for (int j = 4; j < 32; j += 4) {
    x0 = fmaxf(x0, p[j]); x1 = fmaxf(x1, p[j + 1]);
    x2 = fmaxf(x2, p[j + 2]); x3 = fmaxf(x3, p[j + 3]);
  }
  return fmaxf(fmaxf(x0, x1), fmaxf(x2, x3));
}
__device__ __forceinline__ float rsum32(const float (&p)[32]) {
  float x0 = p[0], x1 = p[1], x2 = p[2], x3 = p[3];
#pragma unroll
  for (int j = 4; j < 32; j += 4) { x0 += p[j]; x1 += p[j + 1]; x2 += p[j + 2]; x3 += p[j + 3]; }
  return (x0 + x1) + (x2 + x3);
}

// grid (17, 15, 4), block 256 (4 waves).
__global__ __launch_bounds__(256) void k_flash(const float* __restrict__ qb,
                                               const float* __restrict__ kb,
                                               const float* __restrict__ vb,
                                               float* __restrict__ accp,
                                               float* __restrict__ mlb) {
  __shared__ __align__(16) float ks[4 * 32];
  __shared__ __align__(16) float vs[32 * 32];
  const int tid = threadIdx.x;
  const int ia  = blockIdx.x * 256 + tid;
  const int sp  = blockIdx.y;
  const int b   = blockIdx.z;
  float q[4];
#pragma unroll
  for (int d = 0; d < 4; ++d)
    q[d] = (ia < NN) ? qb[((size_t)b * 4 + d) * NN + ia] : 0.f;
  float m = -1e30f, l = 0.f;
  float acc[32];
#pragma unroll
  for (int c = 0; c < 32; ++c) acc[c] = 0.f;
  const int jbeg = sp * JSPAN;
  const int jend = (jbeg + JSPAN < NN) ? jbeg + JSPAN : NN;
  const int cs = tid >> 3, j4 = (tid & 7) * 4;   // staging coords
  for (int j0 = jbeg; j0 < jend; j0 += 32) {
    const int nv = (jend - j0 < 32) ? jend - j0 : 32;
    __syncthreads();
    {
      const float* vsrc = &vb[((size_t)b * 32 + cs) * NN + j0 + j4];
      float4 v4;
      if (j4 + 4 <= nv) {
        v4 = *(const float4*)vsrc;
      } else {
        v4.x = (j4 + 0 < nv) ? vsrc[0] : 0.f;
        v4.y = (j4 + 1 < nv) ? vsrc[1] : 0.f;
        v4.z = (j4 + 2 < nv) ? vsrc[2] : 0.f;
        v4.w = (j4 + 3 < nv) ? vsrc[3] : 0.f;
      }
      *(float4*)&vs[cs * 32 + j4] = v4;
      if (tid < 32) {
        const int d = tid >> 3;
        const float* ksrc = &kb[((size_t)b * 4 + d) * NN + j0 + j4];
        float4 k4;
        if (j4 + 4 <= nv) {
          k4 = *(const float4*)ksrc;
        } else {
          k4.x = (j4 + 0 < nv) ? ksrc[0] : 0.f;
          k4.y = (j4 + 1 < nv) ? ksrc[1] : 0.f;
          k4.z = (j4 + 2 < nv) ? ksrc[2] : 0.f;
          k4.w = (j4 + 3 < nv) ? ksrc[3] : 0.f;
        }
        *(float4*)&ks[d * 32 + j4] = k4;
      }
    }
    __syncthreads();
    float p[32];
#pragma unroll
    for (int jj = 0; jj < 8; ++jj) {
      float4 k0 = *(const float4*)&ks[0 * 32 + 4 * jj];
      float4 k1 = *(const float4*)&ks[1 * 32 + 4 * jj];
      float4 k2 = *(const float4*)&ks[2 * 32 + 4 * jj];
      float4 k3 = *(const float4*)&ks[3 * 32 + 4 * jj];
      p[4 * jj + 0] = fmaf(q[0], k0.x, fmaf(q[1], k1.x, fmaf(q[2], k2.x, q[3] * k3.x)));
      p[4 * jj + 1] = fmaf(q[0], k0.y, fmaf(q[1], k1.y, fmaf(q[2], k2.y, q[3] * k3.y)));
      p[4 * jj + 2] = fmaf(q[0], k0.z, fmaf(q[1], k1.z, fmaf(q[2], k2.z, q[3] * k3.z)));
      p[4 * jj + 3] = fmaf(q[0], k0.w, fmaf(q[1], k1.w, fmaf(q[2], k2.w, q[3] * k3.w)));
    }
    if (nv < 32) {
#pragma unroll
      for (int j = 0; j < 32; ++j)
        if (j >= nv) p[j] = -1e30f;
    }
    float mn = fmaxf(m, rmax32(p));
    float f = __expf(m - mn);
    m = mn;
#pragma unroll
    for (int j = 0; j < 32; ++j) p[j] = __expf(p[j] - mn);
    l = fmaf(l, f, rsum32(p));
#pragma unroll
    for (int c = 0; c < 32; ++c) acc[c] *= f;
#pragma unroll
    for (int jj = 0; jj < 8; ++jj) {
      float4 p4 = make_float4(p[4 * jj], p[4 * jj + 1], p[4 * jj + 2], p[4 * jj + 3]);
#pragma unroll
      for (int c = 0; c < 32; ++c) {
        float4 vv = *(const float4*)&vs[c * 32 + 4 * jj];
        acc[c] = fmaf(p4.x, vv.x, fmaf(p4.y, vv.y, fmaf(p4.z, vv.z, fmaf(p4.w, vv.w, acc[c]))));
      }
    }
  }
  if (ia < NN) {
    const size_t sb4 = (size_t)(sp * 4 + b);
#pragma unroll
    for (int c = 0; c < 32; ++c)
      accp[(sb4 * 32 + c) * NPAD + ia] = acc[c];
    mlb[(sb4 * 2 + 0) * NPAD + ia] = m;
    mlb[(sb4 * 2 + 1) * NPAD + ia] = l;
  }
}

// ================= combine flash partials -> sa = gamma*attn@v + feat1 ============
// grid (17, 32, 4), block 256.
__global__ __launch_bounds__(256) void k_combine(const float* __restrict__ accp,
                                                 const float* __restrict__ mlb,
                                                 const float* __restrict__ f1,
                                                 const float* __restrict__ gamma,
                                                 float* __restrict__ sa) {
  const int n = blockIdx.x * 256 + threadIdx.x;
  if (n >= NN) return;
  const int c = blockIdx.y, b = blockIdx.z;
  float m[NSPLIT], l[NSPLIT];
#pragma unroll
  for (int s = 0; s < NSPLIT; ++s) {
    m[s] = mlb[((size_t)(s * 4 + b) * 2 + 0) * NPAD + n];
    l[s] = mlb[((size_t)(s * 4 + b) * 2 + 1) * NPAD + n];
  }
  float ms = m[0];
#pragma unroll
  for (int s = 1; s < NSPLIT; ++s) ms = fmaxf(ms, m[s]);
  float den = 0.f, num = 0.f;
#pragma unroll
  for (int s = 0; s < NSPLIT; ++s) {
    float w = __expf(m[s] - ms);
    den = fmaf(l[s], w, den);
    num = fmaf(w, accp[((size_t)(s * 4 + b) * 32 + c) * NPAD + n], num);
  }
  size_t o = ((size_t)b * 32 + c) * NN + n;
  sa[o] = gamma[0] * num / den + f1[o];
}

// ================= CAM: energy (atomic partials) ==============================
__global__ __launch_bounds__(256) void k_zero(float* __restrict__ p) {
  int i = blockIdx.x * 256 + threadIdx.x;
  if (i < 4096) p[i] = 0.f;
}

// grid (17, 4), block 256.
__global__ __launch_bounds__(256) void k_energy(const float* __restrict__ f2,
                                                float* __restrict__ energy) {
  __shared__ float fs[32 * 257];
  const int n0 = blockIdx.x * 256, b = blockIdx.y, tid = threadIdx.x;
  for (int e = tid; e < 32 * 256; e += 256) {
    int c = e >> 8, nl = e & 255;
    int n = n0 + nl;
    fs[c * 257 + nl] = (n < NN) ? f2[((size_t)b * 32 + c) * NN + n] : 0.f;
  }
  __syncthreads();
  const int cg = tid >> 4, dg = tid & 15;
  const int c0 = cg * 2, d0 = dg * 2;
  float e00 = 0.f, e01 = 0.f, e10 = 0.f, e11 = 0.f;
  for (int t = 0; t < 256; ++t) {
    float a0 = fs[c0 * 257 + t], a1 = fs[(c0 + 1) * 257 + t];
    float b0 = fs[d0 * 257 + t], b1 = fs[(d0 + 1) * 257 + t];
    e00 = fmaf(a0, b0, e00); e01 = fmaf(a0, b1, e01);
    e10 = fmaf(a1, b0, e10); e11 = fmaf(a1, b1, e11);
  }
  float* eb = energy + b * 1024;
  atomicAdd(&eb[c0 * 32 + d0], e00);
  atomicAdd(&eb[c0 * 32 + d0 + 1], e01);
  atomicAdd(&eb[(c0 + 1) * 32 + d0], e10);
  atomicAdd(&eb[(c0 + 1) * 32 + d0 + 1], e11);
}

// ======== CAM apply: cattn = softmax(maxE - E) rows; sc = g*cattn@f2 + f2 ========
// grid (65, 4), block 64.
__global__ __launch_bounds__(64) void k_cam(const float* __restrict__ f2,
                                            const float* __restrict__ energy,
                                            const float* __restrict__ gamma,
                                            float* __restrict__ sc) {
  __shared__ __align__(16) float cat[32 * 32];
  const int lane = threadIdx.x, b = blockIdx.y;
  const int n = blockIdx.x * 64 + lane;
  if (lane < 32) {
    const float* eb = energy + b * 1024 + lane * 32;
    float e[32];
#pragma unroll
    for (int d = 0; d < 32; ++d) e[d] = eb[d];
    float mn = e[0];
#pragma unroll
    for (int d = 1; d < 32; ++d) mn = fminf(mn, e[d]);
    float w[32];
    float sum = 0.f;
#pragma unroll
    for (int d = 0; d < 32; ++d) { w[d] = __expf(mn - e[d]); sum += w[d]; }
    float inv = 1.f / sum;
#pragma unroll
    for (int d = 0; d < 32; ++d) cat[lane * 32 + d] = w[d] * inv;
  }
  __syncthreads();
  const bool ok = n < NN;
  float f[32];
#pragma unroll
  for (int c = 0; c < 32; ++c) f[c] = ok ? f2[((size_t)b * 32 + c) * NN + n] : 0.f;
  const float g = gamma[0];
#pragma unroll
  for (int c = 0; c < 32; ++c) {
    float a = 0.f;
#pragma unroll
    for (int k4 = 0; k4 < 8; ++k4) {
      float4 cw = *(const float4*)&cat[c * 32 + 4 * k4];
      a = fmaf(cw.x, f[4 * k4], fmaf(cw.y, f[4 * k4 + 1], fmaf(cw.z, f[4 * k4 + 2], fmaf(cw.w, f[4 * k4 + 3], a))));
    }
    if (ok) sc[((size_t)b * 32 + c) * NN + n] = g * a + f[c];
  }
}

// ======== fused c51(sa)+BN+ReLU, c52(sc)+BN+ReLU, sum, conv8 1x1 -> out ========
// grid (65, 4), block 128.
__global__ __launch_bounds__(128) void k_final(const float* __restrict__ sa,
                                               const float* __restrict__ sc,
                                               const float* __restrict__ w51,
                                               const float* __restrict__ s51, const float* __restrict__ b51,
                                               const float* __restrict__ m51, const float* __restrict__ v51,
                                               const float* __restrict__ w52,
                                               const float* __restrict__ s52, const float* __restrict__ b52,
                                               const float* __restrict__ m52, const float* __restrict__ v52,
                                               const float* __restrict__ w8, const float* __restrict__ b8,
                                               float* __restrict__ out) {
  __shared__ __align__(16) float tin[2 * 8 * 10 * 12];  // 1920
  __shared__ __align__(16) float twt[72 * 64];          // 4608
  __shared__ float tmid[64 * 65];
  const int oh0 = blockIdx.x * 8;
  const int b   = blockIdx.y;
  const int tid = threadIdx.x;
  const int vocg = tid >> 3, oh_l = tid & 7;
  float acc[4][8] = {};
  for (int cc = 0; cc < 4; ++cc) {
    __syncthreads();
    for (int e = tid; e < 1280; e += 128) {
      int which = (e >= 640) ? 1 : 0;
      int r1 = e - which * 640;
      int ci = r1 / 80, r2 = r1 - ci * 80;
      int tr = r2 >> 3, c = r2 & 7;
      int ih = oh0 - 1 + tr;
      int cin = cc * 8 + ci;
      const float* src = which ? sc : sa;
      float v = 0.f;
      if (ih >= 0 && ih < H2) v = src[((size_t)b * 32 + cin) * NN + ih * 8 + c];
      tin[which * 960 + (ci * 10 + tr) * 12 + c] = v;
    }
    for (int e = tid; e < 4608; e += 128) {
      int voc_l = e & 63, t = e >> 6;
      const float* base = (voc_l < 32) ? (w51 + voc_l * 288) : (w52 + (voc_l - 32) * 288);
      twt[t * 64 + voc_l] = base[cc * 8 * 9 + t];
    }
    __syncthreads();
    const float* tbase = tin + (vocg < 8 ? 0 : 960);
#pragma unroll 1
    for (int ci = 0; ci < 8; ++ci) {
#pragma unroll
      for (int kh = 0; kh < 3; ++kh) {
        const float* rp = tbase + (ci * 10 + oh_l + kh) * 12;
        float4 a0 = *(const float4*)rp;
        float4 a1 = *(const float4*)(rp + 4);
        float rr[10];
        rr[0] = 0.f; rr[9] = 0.f;
        rr[1] = a0.x; rr[2] = a0.y; rr[3] = a0.z; rr[4] = a0.w;
        rr[5] = a1.x; rr[6] = a1.y; rr[7] = a1.z; rr[8] = a1.w;
#pragma unroll
        for (int kw = 0; kw < 3; ++kw) {
          float4 wv = *(const float4*)&twt[(ci * 9 + kh * 3 + kw) * 64 + vocg * 4];
#pragma unroll
          for (int ow = 0; ow < 8; ++ow) {
            float r = rr[ow + kw];
            acc[0][ow] = fmaf(r, wv.x, acc[0][ow]);
            acc[1][ow] = fmaf(r, wv.y, acc[1][ow]);
            acc[2][ow] = fmaf(r, wv.z, acc[2][ow]);
            acc[3][ow] = fmaf(r, wv.w, acc[3][ow]);
          }
        }
      }
    }
  }
  {
    float inv[4], sh[4];
#pragma unroll
    for (int vv = 0; vv < 4; ++vv) {
      int voc = vocg * 4 + vv;
      bool A = voc < 32;
      int ci = voc & 31;
      float sN = A ? s51[ci] : s52[ci];
      float bN = A ? b51[ci] : b52[ci];
      float mN = A ? m51[ci] : m52[ci];
      float vN = A ? v51[ci] : v52[ci];
      inv[vv] = sN * rsqrtf(vN + 1e-5f);
      sh[vv] = bN - mN * inv[vv];
    }
#pragma unroll
    for (int ow = 0; ow < 8; ++ow) {
      int pos = oh_l * 8 + ow;
#pragma unroll
      for (int vv = 0; vv < 4; ++vv) {
        float y = acc[vv][ow] * inv[vv] + sh[vv];
        tmid[pos * 65 + vocg * 4 + vv] = frelu(y);
      }
    }
  }
  __syncthreads();
  {
    const int o = tid >> 6, pos = tid & 63;
    const int oh = oh0 + (pos >> 3), ow = pos & 7;
    float a = b8[o];
    const float* wrow = w8 + o * 32;
#pragma unroll
    for (int c = 0; c < 32; ++c)
      a = fmaf(tmid[pos * 65 + c] + tmid[pos * 65 + 32 + c], wrow[c], a);
    if (oh < H2) out[((size_t)b * 2 + o) * NN + oh * 8 + ow] = a;
  }
}

// =========================== launcher ===========================
extern "C" void kernel_launch(void* const* d_in, const int* in_sizes, int n_in,
                              void* d_out, int out_size, void* d_ws, size_t ws_size,
                              hipStream_t stream) {
  (void)in_sizes; (void)n_in; (void)out_size; (void)ws_size;
  const float* x      = (const float*)d_in[0];
  const float* w1     = (const float*)d_in[1];
  const float* b1     = (const float*)d_in[2];
  const float* w2     = (const float*)d_in[3];
  const float* b2     = (const float*)d_in[4];
  const float* w3     = (const float*)d_in[5];
  const float* b3     = (const float*)d_in[6];
  const float* c5a_w  = (const float*)d_in[7];
  const float* bn5a_s = (const float*)d_in[8];
  const float* bn5a_b = (const float*)d_in[9];
  const float* bn5a_m = (const float*)d_in[10];
  const float* bn5a_v = (const float*)d_in[11];
  const float* c5c_w  = (const float*)d_in[12];
  const float* bn5c_s = (const float*)d_in[13];
  const float* bn5c_b = (const float*)d_in[14];
  const float* bn5c_m = (const float*)d_in[15];
  const float* bn5c_v = (const float*)d_in[16];
  const float* c51_w  = (const float*)d_in[17];
  const float* bn51_s = (const float*)d_in[18];
  const float* bn51_b = (const float*)d_in[19];
  const float* bn51_m = (const float*)d_in[20];
  const float* bn51_v = (const float*)d_in[21];
  const float* c52_w  = (const float*)d_in[22];
  const float* bn52_s = (const float*)d_in[23];
  const float* bn52_b = (const float*)d_in[24];
  const float* bn52_m = (const float*)d_in[25];
  const float* bn52_v = (const float*)d_in[26];
  const float* pam_qw = (const float*)d_in[27];
  const float* pam_qb = (const float*)d_in[28];
  const float* pam_kw = (const float*)d_in[29];
  const float* pam_kb = (const float*)d_in[30];
  const float* pam_vw = (const float*)d_in[31];
  const float* pam_vb = (const float*)d_in[32];
  const float* pgamma = (const float*)d_in[33];
  const float* cgamma = (const float*)d_in[34];
  const float* c8_w   = (const float*)d_in[35];
  const float* c8_b   = (const float*)d_in[36];

  float* W    = (float*)d_ws;
  ushort* h1ch = (ushort*)(W + OFF_H1CH);
  ushort* h1cl = (ushort*)(W + OFF_H1CL);
  float* p2   = W + OFF_P2;
  float* p3a  = W + OFF_P3A;
  float* p3b  = W + OFF_P3B;
  float* f1   = W + OFF_F1;
  float* f2   = W + OFF_F2;
  float* qbuf = W + OFF_Q;
  float* kbuf = W + OFF_K;
  float* vbuf = W + OFF_V;
  float* sab  = W + OFF_SA;
  float* scb  = W + OFF_SC;
  float* accp = W + OFF_ACCP;
  float* mlb  = W + OFF_ML;
  float* enb  = W + OFF_EN;
  ushort* w2bh = (ushort*)(W + OFF_W2B);
  ushort* w2bl = (ushort*)(W + OFF_W2B + 409600);
  float* w3T  = W + OFF_W3T;
  float* outp = (float*)d_out;

  k_wcvt<<<dim3(256), 128, 0, stream>>>(w2, w2bh, w2bl);
  k_w3t<<<dim3(2304), 128, 0, stream>>>(w3, w3T);
  k_conv1<<<dim3(65, 16, 4), 256, 0, stream>>>(x, w1, b1, h1ch, h1cl);
  k_conv2<<<dim3(129, 4), 256, 0, stream>>>(h1ch, h1cl, w2bh, w2bl, b2, p2);
  k_conv3<<<dim3(65, 8, 4), 128, 0, stream>>>(p2, w3T, p3a, p3b);
  k_c5<<<dim3(65, 4), 128, 0, stream>>>(p3a, p3b, b3,
                                        c5a_w, bn5a_s, bn5a_b, bn5a_m, bn5a_v,
                                        c5c_w, bn5c_s, bn5c_b, bn5c_m, bn5c_v,
                                        f1, f2);
  k_qkv<<<dim3(17, 40, 4), 256, 0, stream>>>(f1, pam_qw, pam_qb, pam_kw, pam_kb,
                                             pam_vw, pam_vb, qbuf, kbuf, vbuf);
  k_zero<<<dim3(16), 256, 0, stream>>>(enb);
  k_flash<<<dim3(17, NSPLIT, 4), 256, 0, stream>>>(qbuf, kbuf, vbuf, accp, mlb);
  k_energy<<<dim3(17, 4), 256, 0, stream>>>(f2, enb);
  k_combine<<<dim3(17, 32, 4), 256, 0, stream>>>(accp, mlb, f1, pgamma, sab);
  k_cam<<<dim3(65, 4), 64, 0, stream>>>(f2, enb, cgamma, scb);
  k_final<<<dim3(65, 4), 128, 0, stream>>>(sab, scb,
                                           c51_w, bn51_s, bn51_b, bn51_m, bn51_v,
                                           c52_w, bn52_s, bn52_b, bn52_m, bn52_v,
                                           c8_w, c8_b, outp);
}